// Round 10
// baseline (462.532 us; speedup 1.0000x reference)
//
#include <hip/hip_runtime.h>
#include <hip/hip_cooperative_groups.h>
#include <math.h>

namespace cg = cooperative_groups;

typedef unsigned short u16;
typedef unsigned int   u32;
typedef __bf16 bf16x8 __attribute__((ext_vector_type(8)));
typedef float  f32x4  __attribute__((ext_vector_type(4)));

#define LQ   1024     // H*W
#define DM   512      // d_model
#define DI   1024     // d_inner
#define NS   16       // d_state
#define CIN  256
#define EPSF 1e-5f
#define CH   32       // scan chunks
#define TL   32       // chunk length (CH*TL == LQ)
#define NBLK 512      // cooperative grid (2 blocks/CU x 256 CUs)

__device__ __forceinline__ float bf2f(u16 u){ return __uint_as_float(((u32)u)<<16); }
__device__ __forceinline__ u16 f2bf(float f){
  u32 x = __float_as_uint(f);
  x += 0x7fffu + ((x>>16)&1u);           // RNE
  return (u16)(x>>16);
}
__device__ __forceinline__ float sigm(float x){ return 1.f/(1.f+expf(-x)); }

__device__ __forceinline__ void ld8(const u16* p, float* f){
  const uint4 v = *(const uint4*)p;
  f[0]=bf2f((u16)v.x); f[1]=bf2f((u16)(v.x>>16));
  f[2]=bf2f((u16)v.y); f[3]=bf2f((u16)(v.y>>16));
  f[4]=bf2f((u16)v.z); f[5]=bf2f((u16)(v.z>>16));
  f[6]=bf2f((u16)v.w); f[7]=bf2f((u16)(v.w>>16));
}
__device__ __forceinline__ void st8(u16* p, const float* f){
  uint4 v;
  v.x = (u32)f2bf(f[0]) | ((u32)f2bf(f[1])<<16);
  v.y = (u32)f2bf(f[2]) | ((u32)f2bf(f[3])<<16);
  v.z = (u32)f2bf(f[4]) | ((u32)f2bf(f[5])<<16);
  v.w = (u32)f2bf(f[6]) | ((u32)f2bf(f[7])<<16);
  *(uint4*)p = v;
}

// ---- async global->LDS DMA: 16 B per lane, dest = uniform base + lane*16 ----
typedef const __attribute__((address_space(1))) u32* gas_t;
typedef __attribute__((address_space(3))) u32* las_t;
__device__ __forceinline__ void gld16(const void* g, void* l){
  __builtin_amdgcn_global_load_lds((gas_t)g, (las_t)l, 16, 0, 0);
}

// ---- unified MFMA GEMM main loop: TMxTN tile, BK=64, 4 waves (2x2) ----
// LDS: linear [row][64] with XOR-swizzled chunk slots (linear gload_lds dest +
// inverse-swz global SOURCE + swz READ, same involution) -> conflict-free.
template<int TM, int TN>
__device__ __forceinline__ void gemm_main(const u16* __restrict__ A, const u16* __restrict__ B,
                                          int K, u16* As, u16* Bs,
                                          f32x4 (&acc)[TM/32][TN/32], int tid)
{
  const int lane = tid&63, w = tid>>6;
  const int m_off = (w>>1)*(TM/2), n_off = (w&1)*(TN/2);
  const int lr = lane>>3, lp = lane&7;           // stage: lane-row, lane-slot
  const int pos = lp ^ lr;                       // source k-chunk for this slot
  for (int k0=0; k0<K; k0+=64){
    #pragma unroll
    for (int j=0;j<TM/32;++j){
      const int rb = (w*(TM/32)+j)*8;
      gld16(A + (size_t)(rb+lr)*K + k0 + (pos<<3), As + rb*64);
    }
    #pragma unroll
    for (int j=0;j<TN/32;++j){
      const int rb = (w*(TN/32)+j)*8;
      gld16(B + (size_t)(rb+lr)*K + k0 + (pos<<3), Bs + rb*64);
    }
    __syncthreads();
    #pragma unroll
    for (int ks=0;ks<2;++ks){
      const int c = ks*4 + (lane>>4);            // k-chunk this frag wants
      bf16x8 af[TM/32], bb[TN/32];
      #pragma unroll
      for (int mi=0;mi<TM/32;++mi){
        const int R = m_off + mi*16 + (lane&15);
        af[mi] = *(const bf16x8*)(As + R*64 + ((c ^ (R&7))<<3));
      }
      #pragma unroll
      for (int ni=0;ni<TN/32;++ni){
        const int R = n_off + ni*16 + (lane&15);
        bb[ni] = *(const bf16x8*)(Bs + R*64 + ((c ^ (R&7))<<3));
      }
      #pragma unroll
      for (int mi=0;mi<TM/32;++mi)
        #pragma unroll
        for (int ni=0;ni<TN/32;++ni)
          acc[mi][ni] = __builtin_amdgcn_mfma_f32_16x16x32_bf16(af[mi], bb[ni], acc[mi][ni], 0,0,0);
    }
    __syncthreads();
  }
}

struct MegaArgs {
  const float *cr_w, *cr_g, *cr_b, *cr_m, *cr_v;
  const float *rs_w, *rs_g, *rs_b, *rs_m, *rs_v;
  const float *lnVg, *lnVb, *iwV, *AV, *BV, *CV, *owV;
  const float *w1V, *b1V, *w2V, *b2V;
  const float *lnIg, *lnIb, *iwI, *AI, *BI, *CI, *owI;
  const float *w1I, *b1I, *w2I, *b2I;
  const float *xV, *xI;
  float* out;
  float* xr; u16* xn; float* lam;
  u16 *iwVb, *iwIb, *owTV, *owTI, *rswb, *crwb, *xT, *W2b;
  float* part; u16 *xp, *comb, *hfin;
};

__device__ __forceinline__ void cvt_range(const float* __restrict__ s, u16* __restrict__ d,
                                          int n, int g){
  for (int i = g*4; i < n; i += NBLK*256*4){
    const float4 v = *(const float4*)(s+i);
    ushort4 o; o.x=f2bf(v.x); o.y=f2bf(v.y); o.z=f2bf(v.z); o.w=f2bf(v.w);
    *(ushort4*)(d+i) = o;
  }
}

// ---- phase device functions (shared by mega and fallback kernels) ----

__device__ __forceinline__ void dev_prep(const MegaArgs& P, int blk, int tid, char* smem)
{
  const int g = blk*256 + tid;
  cvt_range(P.iwV,  P.iwVb, 1048576, g);
  cvt_range(P.iwI,  P.iwIb, 1048576, g);
  cvt_range(P.cr_w, P.crwb, 131072,  g);
  cvt_range(P.rs_w, P.rswb, 131072,  g);
  float (*tile)[33] = (float(*)[33])smem;
  for (int t = blk; t < 2048; t += NBLK){        // exactly 4 iters per block
    int R, r0, c0; const float* src; u16* dst;
    if (t < 1024){
      const int zz = t>>9, rem = t&511;
      R = 512; r0 = (rem>>5)*32; c0 = (rem&31)*32;
      src = zz? P.owI : P.owV;  dst = zz? P.owTI : P.owTV;
    } else {
      const int tt = t-1024, img = tt>>8, rem = tt&255;
      R = 256; r0 = (rem>>5)*32; c0 = (rem&31)*32;
      src = (img<2 ? P.xV : P.xI) + (size_t)(img&1)*CIN*LQ;
      dst = P.xT + (size_t)img*LQ*CIN;
    }
    __syncthreads();
    {
      const int r = tid>>3, c = (tid&7)*4;
      const float4 v = *(const float4*)(src + (size_t)(r0+r)*1024 + c0 + c);
      tile[r][c]=v.x; tile[r][c+1]=v.y; tile[r][c+2]=v.z; tile[r][c+3]=v.w;
    }
    __syncthreads();
    {
      const int cl = tid>>3, rl = (tid&7)*4;
      ushort4 o;
      o.x = f2bf(tile[rl+0][cl]); o.y = f2bf(tile[rl+1][cl]);
      o.z = f2bf(tile[rl+2][cl]); o.w = f2bf(tile[rl+3][cl]);
      *(ushort4*)(dst + (size_t)(c0+cl)*R + r0 + rl) = o;
    }
  }
}

// P1: k1 conv-raise GEMM (all 512) + W2 pre-GEMM (blocks 0..31, second task)
__device__ __forceinline__ void dev_p1(const MegaArgs& P, int blk, int tid, char* smem)
{
  const int lane = tid&63, w = tid>>6;
  {
    const int m0 = (blk>>3)*64, n0 = (blk&7)*64;
    u16* As = (u16*)smem; u16* Bs = (u16*)(smem+8192);
    f32x4 acc[2][2];
    const f32x4 z = {0.f,0.f,0.f,0.f};
    #pragma unroll
    for (int mi=0;mi<2;++mi) for (int ni=0;ni<2;++ni) acc[mi][ni]=z;
    gemm_main<64,64>(P.xT + (size_t)m0*CIN, P.crwb + (size_t)n0*CIN, CIN, As, Bs, acc, tid);
    #pragma unroll
    for (int mi=0;mi<2;++mi)
      #pragma unroll
      for (int ni=0;ni<2;++ni){
        const int n = n0 + (w&1)*32 + ni*16 + (lane&15);
        const float s = P.cr_g[n]*rsqrtf(P.cr_v[n]+EPSF);
        const float t = P.cr_b[n] - P.cr_m[n]*s;
        #pragma unroll
        for (int rr=0;rr<4;++rr){
          const int m = m0 + (w>>1)*32 + mi*16 + ((lane>>4)<<2) + rr;
          P.xr[(size_t)m*DM + n] = fmaxf(fmaf(acc[mi][ni][rr], s, t), 0.f);
        }
      }
  }
  if (blk < 32){
    const int p = blk>>4, rem = blk&15;
    const int m0b = (rem>>3)*128, n0b = (rem&7)*128;
    u16* As2 = (u16*)smem; u16* Bs2 = (u16*)(smem+16384);
    f32x4 acc2[4][4];
    const f32x4 z = {0.f,0.f,0.f,0.f};
    #pragma unroll
    for (int mi=0;mi<4;++mi) for (int ni=0;ni<4;++ni) acc2[mi][ni]=z;
    gemm_main<128,128>(P.rswb + (size_t)m0b*DM, (p? P.owTI : P.owTV) + (size_t)n0b*DM,
                       DM, As2, Bs2, acc2, tid);
    u16* __restrict__ orow = P.W2b + (size_t)p*256*1024;
    #pragma unroll
    for (int mi=0;mi<4;++mi)
      #pragma unroll
      for (int rr=0;rr<4;++rr){
        const int m = m0b + (w>>1)*64 + mi*16 + ((lane>>4)<<2) + rr;
        #pragma unroll
        for (int ni=0;ni<4;++ni){
          const int n = n0b + (w&1)*64 + ni*16 + (lane&15);
          orow[(size_t)m*1024 + n] = f2bf(acc2[mi][ni][rr]);
        }
      }
  }
}

// P2: fused LN -> bf16 xn + pool partials (tasks 0..63)
__device__ __forceinline__ void dev_k2f(const MegaArgs& P, int blk, int tid, char* smem)
{
  const int sl = blk&15, img = blk>>4, p = img>>1;
  const int l = tid&63, w = tid>>6;
  float* pw = (float*)smem;                    // [4][512]
  const float* lg = (p? P.lnIg : P.lnVg) + l*8;
  const float* lb = (p? P.lnIb : P.lnVb) + l*8;
  float g8[8], b8[8];
  *(float4*)&g8[0] = *(const float4*)lg;  *(float4*)&g8[4] = *(const float4*)(lg+4);
  *(float4*)&b8[0] = *(const float4*)lb;  *(float4*)&b8[4] = *(const float4*)(lb+4);
  float acc[8] = {};
  const int rbase = img*1024 + sl*64 + w*16;
  for (int r=0; r<16; ++r){
    const int row = rbase + r;
    const float* base = P.xr + (size_t)row*DM + l*8;
    float v[8];
    *(float4*)&v[0] = *(const float4*)(base);
    *(float4*)&v[4] = *(const float4*)(base+4);
    float s=0.f, q=0.f;
    #pragma unroll
    for (int j=0;j<8;++j){ s += v[j]; q += v[j]*v[j]; acc[j] += v[j]; }
    #pragma unroll
    for (int off=32; off; off>>=1){ s += __shfl_down(s,off); q += __shfl_down(q,off); }
    s = __shfl(s,0); q = __shfl(q,0);
    const float mean = s*(1.f/DM);
    const float rstd = rsqrtf(fmaxf(q*(1.f/DM) - mean*mean, 0.f)+EPSF);
    float y[8];
    #pragma unroll
    for (int j=0;j<8;++j) y[j] = (v[j]-mean)*rstd*g8[j] + b8[j];
    st8(P.xn + (size_t)row*DM + l*8, y);
  }
  #pragma unroll
  for (int j=0;j<8;++j) pw[w*512 + l*8+j] = acc[j];
  __syncthreads();
  for (int ch=tid; ch<DM; ch+=256)
    P.part[((size_t)img*16 + sl)*DM + ch] = pw[ch]+pw[512+ch]+pw[1024+ch]+pw[1536+ch];
}

__device__ __forceinline__ void dev_lambda(const MegaArgs& P, int img, int tid, char* smem)
{
  const int p = img>>1;
  const float* w1 = p? P.w1I : P.w1V;  const float* b1 = p? P.b1I : P.b1V;
  const float* w2 = p? P.w2I : P.w2V;  const float* b2 = p? P.b2I : P.b2V;
  float* pool = (float*)smem;          // [512]
  float* hb   = pool + DM;             // [128]
  for (int ch=tid; ch<DM; ch+=256){
    float s=0.f;
    #pragma unroll
    for (int sl=0; sl<16; ++sl) s += P.part[((size_t)img*16 + sl)*DM + ch];
    pool[ch] = s * (1.f/LQ);
  }
  __syncthreads();
  if (tid<128){
    float h = b1[tid];
    const float* wr = w1 + (size_t)tid*DM;
    for (int o=0;o<DM;o+=4){
      const float4 wv = *(const float4*)(wr+o);
      h += pool[o]*wv.x + pool[o+1]*wv.y + pool[o+2]*wv.z + pool[o+3]*wv.w;
    }
    hb[tid] = fmaxf(h,0.f);
  }
  __syncthreads();
  if (tid==0){
    float v = b2[0];
    for (int j=0;j<128;++j) v += hb[j]*w2[j];
    P.lam[img] = sigm(v);
  }
}

// P3: k3 in-proj GEMM (tasks 0..511)
__device__ __forceinline__ void dev_k3(const MegaArgs& P, int blk, int tid, char* smem)
{
  const int lane = tid&63, w = tid>>6;
  const int p = blk>>8, rem = blk&255;
  const int m0 = (rem>>4)*128, n0 = (rem&15)*128;
  const u16* A  = P.xn + (size_t)p*2048*DM;
  const u16* Bw = p? P.iwIb : P.iwVb;
  u16* As = (u16*)smem; u16* Bs = (u16*)(smem+16384);
  f32x4 acc[4][4];
  const f32x4 z = {0.f,0.f,0.f,0.f};
  #pragma unroll
  for (int mi=0;mi<4;++mi) for (int ni=0;ni<4;++ni) acc[mi][ni]=z;
  gemm_main<128,128>(A + (size_t)m0*DM, Bw + (size_t)n0*DM, DM, As, Bs, acc, tid);
  u16* __restrict__ orow = P.xp + (size_t)p*2048*2048;
  #pragma unroll
  for (int mi=0;mi<4;++mi)
    #pragma unroll
    for (int rr=0;rr<4;++rr){
      const int m = m0 + (w>>1)*64 + mi*16 + ((lane>>4)<<2) + rr;
      #pragma unroll
      for (int ni=0;ni<4;++ni){
        const int n = n0 + (w&1)*64 + ni*16 + (lane&15);
        orow[(size_t)m*2048 + n] = f2bf(acc[mi][ni][rr]);
      }
    }
}

// P4: scan sweep 1 (raw chunk finals), tasks 0..511
__device__ __forceinline__ void dev_k4s1(const MegaArgs& P, int blk, int tid, char* smem)
{
  const int p = blk>>8, rem = blk&255;
  const int c = rem>>3, rb = rem&7;
  const int row = rb*256 + tid;
  const int bb = rb>>2, il = (rb&3)*256, i = il + tid;
  u16* xs = (u16*)smem;                   // 16 KB
  {
    const u16* src = P.xp + ((size_t)(p*2048 + bb*1024 + c*TL))*2048 + il;
    const int r0 = tid>>5, cb = (tid&31)*8;
    #pragma unroll
    for (int rr=0; rr<TL; rr+=8)
      *(uint4*)(xs + (rr+r0)*256 + cb) = *(const uint4*)(src + (size_t)(rr+r0)*2048 + cb);
  }
  const float* Al = p? P.AI : P.AV;
  float a[16], uf[16], ub[16];
  #pragma unroll
  for (int s=0;s<16;s+=4){
    const float4 al = *(const float4*)(Al + (size_t)i*NS + s);
    a[s]=-expf(al.x); a[s+1]=-expf(al.y); a[s+2]=-expf(al.z); a[s+3]=-expf(al.w);
    uf[s]=0.f; uf[s+1]=0.f; uf[s+2]=0.f; uf[s+3]=0.f;
    ub[s]=0.f; ub[s+1]=0.f; ub[s+2]=0.f; ub[s+3]=0.f;
  }
  __syncthreads();
  #pragma unroll 4
  for (int tt=0; tt<TL; ++tt){
    const float xf = bf2f(xs[tt*256 + tid]);
    const float xb = bf2f(xs[(TL-1-tt)*256 + tid]);
    #pragma unroll
    for (int s=0;s<16;++s){
      uf[s] = fmaf(uf[s], a[s], xf);
      ub[s] = fmaf(ub[s], a[s], xb);
    }
  }
  u16* hpf = P.hfin + (((size_t)(p*2+0)*CH + c)*2048 + row)*NS;
  u16* hpb = P.hfin + (((size_t)(p*2+1)*CH + c)*2048 + row)*NS;
  st8(hpf, uf); st8(hpf+8, uf+8);
  st8(hpb, ub); st8(hpb+8, ub+8);
}

// P5: scan sweep 2 — in-register chunk prefix + register row-totals (no ps LDS)
__device__ __forceinline__ void dev_k4s2(const MegaArgs& P, int blk, int tid, char* smem)
{
  const int p = blk>>8, rem = blk&255;
  const int c = rem>>3, rb = rem&7;
  const int row = rb*256 + tid;
  const int bb = rb>>2, il = (rb&3)*256, i = il + tid;
  u16* xs = (u16*)smem;                   // 16 KB only
  {
    const u16* src = P.xp + ((size_t)(p*2048 + bb*1024 + c*TL))*2048 + il;
    const int r0 = tid>>5, cb = (tid&31)*8;
    #pragma unroll
    for (int rr=0; rr<TL; rr+=8)
      *(uint4*)(xs + (rr+r0)*256 + cb) = *(const uint4*)(src + (size_t)(rr+r0)*2048 + cb);
  }
  const float* Al = p? P.AI : P.AV;
  const float* B0 = p? P.BI : P.BV;
  const float* B1 = p? P.BV : P.BI;
  const float* Cm = p? P.CI : P.CV;
  const float lm = P.lam[p*2+bb];
  float a[16], aT[16], dmix[16], uf[16], ub[16];
  #pragma unroll
  for (int s=0;s<16;s+=4){
    const float4 al = *(const float4*)(Al + (size_t)i*NS + s);
    const float4 b0 = *(const float4*)(B0 + (size_t)i*NS + s);
    const float4 b1 = *(const float4*)(B1 + (size_t)i*NS + s);
    const float4 cv = *(const float4*)(Cm + (size_t)i*NS + s);
    a[s]=-expf(al.x); a[s+1]=-expf(al.y); a[s+2]=-expf(al.z); a[s+3]=-expf(al.w);
    aT[s]  =expf((float)TL*al.x); aT[s+1]=expf((float)TL*al.y);
    aT[s+2]=expf((float)TL*al.z); aT[s+3]=expf((float)TL*al.w);
    dmix[s]  =(lm*b0.x+(1.f-lm)*b1.x)*cv.x;
    dmix[s+1]=(lm*b0.y+(1.f-lm)*b1.y)*cv.y;
    dmix[s+2]=(lm*b0.z+(1.f-lm)*b1.z)*cv.z;
    dmix[s+3]=(lm*b0.w+(1.f-lm)*b1.w)*cv.w;
    uf[s]=0.f; uf[s+1]=0.f; uf[s+2]=0.f; uf[s+3]=0.f;
    ub[s]=0.f; ub[s+1]=0.f; ub[s+2]=0.f; ub[s+3]=0.f;
  }
  const size_t cstride = (size_t)2048*NS;
  {
    const u16* hb = P.hfin + ((size_t)(p*2+0)*CH*2048 + row)*NS;
    if (c > 0){
      float fin[16];
      ld8(hb, fin); ld8(hb+8, fin+8);
      for (int j=1; j<c; ++j){
        float nx[16];
        ld8(hb + (size_t)j*cstride, nx); ld8(hb + (size_t)j*cstride + 8, nx+8);
        #pragma unroll
        for (int s=0;s<16;++s) uf[s] = fmaf(aT[s], uf[s], fin[s]);
        #pragma unroll
        for (int s=0;s<16;++s) fin[s] = nx[s];
      }
      #pragma unroll
      for (int s=0;s<16;++s) uf[s] = fmaf(aT[s], uf[s], fin[s]);
    }
  }
  {
    const u16* hb = P.hfin + ((size_t)(p*2+1)*CH*2048 + row)*NS;
    if (c < CH-1){
      float fin[16];
      ld8(hb + (size_t)(CH-1)*cstride, fin); ld8(hb + (size_t)(CH-1)*cstride + 8, fin+8);
      for (int j=CH-2; j>c; --j){
        float nx[16];
        ld8(hb + (size_t)j*cstride, nx); ld8(hb + (size_t)j*cstride + 8, nx+8);
        #pragma unroll
        for (int s=0;s<16;++s) ub[s] = fmaf(aT[s], ub[s], fin[s]);
        #pragma unroll
        for (int s=0;s<16;++s) fin[s] = nx[s];
      }
      #pragma unroll
      for (int s=0;s<16;++s) ub[s] = fmaf(aT[s], ub[s], fin[s]);
    }
  }
  __syncthreads();
  // register row-totals: tot[tt] = yf(tt) + yb(row tt); static indices via full unroll
  float tot[TL];
  #pragma unroll
  for (int tt=0; tt<TL; ++tt) tot[tt] = 0.f;
  #pragma unroll
  for (int tt=0; tt<TL; ++tt){
    const float xf = bf2f(xs[tt*256 + tid]);
    const float xb = bf2f(xs[(TL-1-tt)*256 + tid]);
    float yf0=0.f, yf1=0.f, yb0=0.f, yb1=0.f;
    #pragma unroll
    for (int s=0;s<16;s+=2){
      uf[s]   = fmaf(uf[s],   a[s],   xf);
      uf[s+1] = fmaf(uf[s+1], a[s+1], xf);
      ub[s]   = fmaf(ub[s],   a[s],   xb);
      ub[s+1] = fmaf(ub[s+1], a[s+1], xb);
      yf0 = fmaf(uf[s],   dmix[s],   yf0);
      yf1 = fmaf(uf[s+1], dmix[s+1], yf1);
      yb0 = fmaf(ub[s],   dmix[s],   yb0);
      yb1 = fmaf(ub[s+1], dmix[s+1], yb1);
    }
    tot[tt]      += (yf0+yf1)+(0.f);
    tot[TL-1-tt] += (yb0+yb1);
  }
  // epilogue: comb = 0.5*silu(g)*tot, coalesced 2B/lane per row
  #pragma unroll
  for (int tt=0; tt<TL; ++tt){
    const size_t mrow = (size_t)(p*2048 + bb*1024 + c*TL + tt);
    const float g = bf2f(P.xp[mrow*2048 + DI + i]);
    P.comb[mrow*(size_t)DI + i] = f2bf(0.5f*g*sigm(g)*tot[tt]);
  }
}

// P6: fused out-proj GEMM + BN + residual, tasks 0..511 (32x64 tiles)
__device__ __forceinline__ void dev_k5(const MegaArgs& P, int blk, int tid, char* smem)
{
  const int lane = tid&63, w = tid>>6;
  const int p = blk>>8, rem = blk&255;
  const int m0 = (rem>>2)*32, n0 = (rem&3)*64;
  const u16* A = P.comb + (size_t)p*2048*DI;
  const u16* B = P.W2b + (size_t)p*256*1024;
  u16* As = (u16*)smem; u16* Bs = (u16*)(smem+4096);
  f32x4 acc[1][2];
  const f32x4 z = {0.f,0.f,0.f,0.f};
  acc[0][0]=z; acc[0][1]=z;
  gemm_main<32,64>(A + (size_t)m0*DI, B + (size_t)n0*DI, DI, As, Bs, acc, tid);
  const int bb = m0>>10;
  const int img = p*2 + bb;
  const float* xres = (p? P.xI : P.xV) + (size_t)bb*CIN*LQ;
  float* obase = P.out + (size_t)img*CIN*LQ;
  #pragma unroll
  for (int ni=0;ni<2;++ni){
    const int q = n0 + (w&1)*32 + ni*16 + (lane&15);
    const float s = P.rs_g[q]*rsqrtf(P.rs_v[q]+EPSF);
    const float t = P.rs_b[q] - P.rs_m[q]*s;
    const int m = m0 + (w>>1)*16 + ((lane>>4)<<2);
    const int hw = m & 1023;
    const float4 xv = *(const float4*)(xres + (size_t)q*LQ + hw);
    float4 o;
    o.x = fmaf(acc[0][ni][0], s, t) + xv.x;
    o.y = fmaf(acc[0][ni][1], s, t) + xv.y;
    o.z = fmaf(acc[0][ni][2], s, t) + xv.z;
    o.w = fmaf(acc[0][ni][3], s, t) + xv.w;
    *(float4*)(obase + (size_t)q*LQ + hw) = o;
  }
}

// ==================== cooperative mega-kernel (32 KB LDS max) ====================
__global__ __launch_bounds__(256,2) void mega(MegaArgs P)
{
  cg::grid_group grid = cg::this_grid();
  __shared__ __align__(16) char smem[32768];
  const int blk = blockIdx.x, tid = threadIdx.x;
  dev_prep(P, blk, tid, smem);
  grid.sync();
  dev_p1(P, blk, tid, smem);
  grid.sync();
  if (blk < 64) dev_k2f(P, blk, tid, smem);
  grid.sync();
  dev_k3(P, blk, tid, smem);
  grid.sync();
  dev_k4s1(P, blk, tid, smem);
  if (blk < 4){ __syncthreads(); dev_lambda(P, blk, tid, smem); }
  grid.sync();
  dev_k4s2(P, blk, tid, smem);
  grid.sync();
  dev_k5(P, blk, tid, smem);
}

// ==================== fallback multi-kernel pipeline ====================
__global__ __launch_bounds__(256) void kk_prep(MegaArgs P){
  __shared__ __align__(16) char smem[4352];
  dev_prep(P, blockIdx.x, threadIdx.x, smem);
}
__global__ __launch_bounds__(256) void kk_p1(MegaArgs P){
  __shared__ __align__(16) char smem[32768];
  dev_p1(P, blockIdx.x, threadIdx.x, smem);
}
__global__ __launch_bounds__(256) void kk_p2(MegaArgs P){
  __shared__ __align__(16) char smem[8192];
  dev_k2f(P, blockIdx.x, threadIdx.x, smem);
}
__global__ __launch_bounds__(256) void kk_p3(MegaArgs P){
  __shared__ __align__(16) char smem[32768];
  dev_k3(P, blockIdx.x, threadIdx.x, smem);
}
__global__ __launch_bounds__(256) void kk_p4(MegaArgs P){
  __shared__ __align__(16) char smem[16384];
  if (blockIdx.x < NBLK) dev_k4s1(P, blockIdx.x, threadIdx.x, smem);
  else                   dev_lambda(P, blockIdx.x - NBLK, threadIdx.x, smem);
}
__global__ __launch_bounds__(256) void kk_p5(MegaArgs P){
  __shared__ __align__(16) char smem[16384];
  dev_k4s2(P, blockIdx.x, threadIdx.x, smem);
}
__global__ __launch_bounds__(256) void kk_p6(MegaArgs P){
  __shared__ __align__(16) char smem[12288];
  dev_k5(P, blockIdx.x, threadIdx.x, smem);
}

extern "C" void kernel_launch(void* const* d_in, const int* in_sizes, int n_in,
                              void* d_out, int out_size, void* d_ws, size_t ws_size,
                              hipStream_t stream)
{
  char* ws = (char*)d_ws;
  MegaArgs P;
  P.cr_w = (const float*)d_in[0];  P.cr_g = (const float*)d_in[1];
  P.cr_b = (const float*)d_in[2];  P.cr_m = (const float*)d_in[3];
  P.cr_v = (const float*)d_in[4];
  P.rs_w = (const float*)d_in[5];  P.rs_g = (const float*)d_in[6];
  P.rs_b = (const float*)d_in[7];  P.rs_m = (const float*)d_in[8];
  P.rs_v = (const float*)d_in[9];
  P.lnVg = (const float*)d_in[10]; P.lnVb = (const float*)d_in[11];
  P.iwV  = (const float*)d_in[12]; P.AV   = (const float*)d_in[13];
  P.BV   = (const float*)d_in[14]; P.CV   = (const float*)d_in[15];
  P.owV  = (const float*)d_in[16];
  P.w1V  = (const float*)d_in[17]; P.b1V  = (const float*)d_in[18];
  P.w2V  = (const float*)d_in[19]; P.b2V  = (const float*)d_in[20];
  P.lnIg = (const float*)d_in[21]; P.lnIb = (const float*)d_in[22];
  P.iwI  = (const float*)d_in[23]; P.AI   = (const float*)d_in[24];
  P.BI   = (const float*)d_in[25]; P.CI   = (const float*)d_in[26];
  P.owI  = (const float*)d_in[27];
  P.w1I  = (const float*)d_in[28]; P.b1I  = (const float*)d_in[29];
  P.w2I  = (const float*)d_in[30]; P.b2I  = (const float*)d_in[31];
  P.xV   = (const float*)d_in[32]; P.xI   = (const float*)d_in[33];
  P.out  = (float*)d_out;
  // ws layout (~47.8 MB peak):
  P.xr   = (float*)(ws + 0);            // [4096][512] f32          8,388,608
  P.xn   = (u16*)  (ws + 8388608);      // [2][2048][512] bf16      4,194,304
  P.lam  = (float*)(ws + 12582912);     // [4] f32 (+pad)                 512
  P.iwVb = (u16*)  (ws + 12583424);     // [2048][512] bf16         2,097,152
  P.iwIb = (u16*)  (ws + 14680576);     // [2048][512] bf16         2,097,152
  P.owTV = (u16*)  (ws + 16777728);     // [1024][512] bf16         1,048,576
  P.owTI = (u16*)  (ws + 17826304);     // [1024][512] bf16         1,048,576
  P.rswb = (u16*)  (ws + 18874880);     // [256][512] bf16            262,144
  P.crwb = (u16*)  (ws + 19137024);     // [512][256] bf16            262,144
  P.xT   = (u16*)  (ws + 19399168);     // [4][1024][256] bf16      2,097,152
  P.W2b  = (u16*)  (ws + 21496320);     // [2][256][1024] bf16      1,048,576
  P.part = (float*)(ws + 22544896);     // [4][16][512] f32           131,072
  P.xp   = (u16*)  (ws + 22675968);     // [2][2048][2048] bf16    16,777,216
  P.comb = (u16*)  (ws + 39453184);     // [2][2048][1024] bf16     8,388,608
  P.hfin = (u16*)  (ws + 0);            // [4][32][2048][16] bf16   8,388,608 (aliases xr; xr dead after P2)

  void* kargs[] = { (void*)&P };
  hipError_t err = hipLaunchCooperativeKernel((void*)mega, dim3(NBLK), dim3(256),
                                              kargs, 0, stream);
  if (err != hipSuccess){
    (void)hipGetLastError();             // clear sticky error, use fallback path
    kk_prep<<<dim3(NBLK),  dim3(256), 0, stream>>>(P);
    kk_p1  <<<dim3(NBLK),  dim3(256), 0, stream>>>(P);
    kk_p2  <<<dim3(64),    dim3(256), 0, stream>>>(P);
    kk_p3  <<<dim3(NBLK),  dim3(256), 0, stream>>>(P);
    kk_p4  <<<dim3(NBLK+4),dim3(256), 0, stream>>>(P);
    kk_p5  <<<dim3(NBLK),  dim3(256), 0, stream>>>(P);
    kk_p6  <<<dim3(NBLK),  dim3(256), 0, stream>>>(P);
  }
}

// Round 11
// 109.686 us; speedup vs baseline: 4.2169x; 4.2169x over previous
//
#include <hip/hip_runtime.h>
#include <math.h>

typedef unsigned short u16;
typedef unsigned int   u32;
typedef __bf16 bf16x8 __attribute__((ext_vector_type(8)));
typedef float  f32x4  __attribute__((ext_vector_type(4)));

#define LQ   1024     // H*W
#define DM   512      // d_model
#define DI   1024     // d_inner
#define NS   16       // d_state
#define CIN  256
#define EPSF 1e-5f
#define CH   32       // scan chunks
#define TL   32       // chunk length (CH*TL == LQ)
#define NBLK 512

__device__ __forceinline__ float bf2f(u16 u){ return __uint_as_float(((u32)u)<<16); }
__device__ __forceinline__ u16 f2bf(float f){
  u32 x = __float_as_uint(f);
  x += 0x7fffu + ((x>>16)&1u);           // RNE
  return (u16)(x>>16);
}
__device__ __forceinline__ float sigm(float x){ return 1.f/(1.f+expf(-x)); }

__device__ __forceinline__ void ld8(const u16* p, float* f){
  const uint4 v = *(const uint4*)p;
  f[0]=bf2f((u16)v.x); f[1]=bf2f((u16)(v.x>>16));
  f[2]=bf2f((u16)v.y); f[3]=bf2f((u16)(v.y>>16));
  f[4]=bf2f((u16)v.z); f[5]=bf2f((u16)(v.z>>16));
  f[6]=bf2f((u16)v.w); f[7]=bf2f((u16)(v.w>>16));
}
__device__ __forceinline__ void st8(u16* p, const float* f){
  uint4 v;
  v.x = (u32)f2bf(f[0]) | ((u32)f2bf(f[1])<<16);
  v.y = (u32)f2bf(f[2]) | ((u32)f2bf(f[3])<<16);
  v.z = (u32)f2bf(f[4]) | ((u32)f2bf(f[5])<<16);
  v.w = (u32)f2bf(f[6]) | ((u32)f2bf(f[7])<<16);
  *(uint4*)p = v;
}

// ---- async global->LDS DMA: 16 B per lane, dest = uniform base + lane*16 ----
typedef const __attribute__((address_space(1))) u32* gas_t;
typedef __attribute__((address_space(3))) u32* las_t;
__device__ __forceinline__ void gld16(const void* g, void* l){
  __builtin_amdgcn_global_load_lds((gas_t)g, (las_t)l, 16, 0, 0);
}

// ---- double-buffered MFMA GEMM: stage(t+1) BEFORE compute(t), counted vmcnt ----
// LDS: linear [row][64] with XOR-swizzled chunk slots (linear gload_lds dest +
// inverse-swz global SOURCE + swz READ, same involution) -> conflict-free.
// smem carve: As0 | As1 | Bs0 | Bs1 = (TM+TN)*256 bytes.
template<int TM, int TN>
__device__ __forceinline__ void gemm_dbuf(const u16* __restrict__ A, const u16* __restrict__ B,
                                          int K, u16* sm, f32x4 (&acc)[TM/32][TN/32], int tid)
{
  const int lane = tid&63, w = tid>>6;
  const int m_off = (w>>1)*(TM/2), n_off = (w&1)*(TN/2);
  const int lr = lane>>3, lp = lane&7, pos = lp ^ lr;
  u16* Asb[2] = { sm,            sm + TM*64 };
  u16* Bsb[2] = { sm + 2*TM*64,  sm + 2*TM*64 + TN*64 };
  const int NT = K>>6;
  constexpr int NV = TM/32 + TN/32;       // gld16s per wave per tile
  // prologue: stage tile 0 into buf0
  #pragma unroll
  for (int j=0;j<TM/32;++j){
    const int rb=(w*(TM/32)+j)*8;
    gld16(A + (size_t)(rb+lr)*K + (pos<<3), Asb[0] + rb*64);
  }
  #pragma unroll
  for (int j=0;j<TN/32;++j){
    const int rb=(w*(TN/32)+j)*8;
    gld16(B + (size_t)(rb+lr)*K + (pos<<3), Bsb[0] + rb*64);
  }
  for (int t=0;t<NT;++t){
    const int cur = t&1, nxt = cur^1;
    if (t+1 < NT){
      const int k0 = (t+1)<<6;
      #pragma unroll
      for (int j=0;j<TM/32;++j){
        const int rb=(w*(TM/32)+j)*8;
        gld16(A + (size_t)(rb+lr)*K + k0 + (pos<<3), Asb[nxt] + rb*64);
      }
      #pragma unroll
      for (int j=0;j<TN/32;++j){
        const int rb=(w*(TN/32)+j)*8;
        gld16(B + (size_t)(rb+lr)*K + k0 + (pos<<3), Bsb[nxt] + rb*64);
      }
      // wait for tile t's loads only; tile t+1's NV stay in flight
      if constexpr (NV==8)      asm volatile("s_waitcnt vmcnt(8)" ::: "memory");
      else if constexpr (NV==4) asm volatile("s_waitcnt vmcnt(4)" ::: "memory");
      else                      asm volatile("s_waitcnt vmcnt(3)" ::: "memory");
    } else {
      asm volatile("s_waitcnt vmcnt(0)" ::: "memory");
    }
    __builtin_amdgcn_sched_barrier(0);
    __builtin_amdgcn_s_barrier();          // all waves' tile-t loads landed
    __builtin_amdgcn_sched_barrier(0);
    const u16* Ac = Asb[cur]; const u16* Bc = Bsb[cur];
    #pragma unroll
    for (int ks=0;ks<2;++ks){
      const int c = ks*4 + (lane>>4);
      bf16x8 af[TM/32], bb[TN/32];
      #pragma unroll
      for (int mi=0;mi<TM/32;++mi){
        const int R = m_off + mi*16 + (lane&15);
        af[mi] = *(const bf16x8*)(Ac + R*64 + ((c ^ (R&7))<<3));
      }
      #pragma unroll
      for (int ni=0;ni<TN/32;++ni){
        const int R = n_off + ni*16 + (lane&15);
        bb[ni] = *(const bf16x8*)(Bc + R*64 + ((c ^ (R&7))<<3));
      }
      #pragma unroll
      for (int mi=0;mi<TM/32;++mi)
        #pragma unroll
        for (int ni=0;ni<TN/32;++ni)
          acc[mi][ni] = __builtin_amdgcn_mfma_f32_16x16x32_bf16(af[mi], bb[ni], acc[mi][ni], 0,0,0);
    }
    __builtin_amdgcn_sched_barrier(0);
    __builtin_amdgcn_s_barrier();          // buf[cur] free for overwrite at t+1
  }
}

struct MegaArgs {
  const float *cr_w, *cr_g, *cr_b, *cr_m, *cr_v;
  const float *rs_w, *rs_g, *rs_b, *rs_m, *rs_v;
  const float *lnVg, *lnVb, *iwV, *AV, *BV, *CV, *owV;
  const float *w1V, *b1V, *w2V, *b2V;
  const float *lnIg, *lnIb, *iwI, *AI, *BI, *CI, *owI;
  const float *w1I, *b1I, *w2I, *b2I;
  const float *xV, *xI;
  float* out;
  float* xr; u16* xn; float* lam;
  u16 *iwVb, *iwIb, *owTV, *owTI, *rswb, *crwb, *xT, *W2b;
  float* part; u16 *xp, *comb, *hfin;
};

__device__ __forceinline__ void cvt_range(const float* __restrict__ s, u16* __restrict__ d,
                                          int n, int g){
  for (int i = g*4; i < n; i += NBLK*256*4){
    const float4 v = *(const float4*)(s+i);
    ushort4 o; o.x=f2bf(v.x); o.y=f2bf(v.y); o.z=f2bf(v.z); o.w=f2bf(v.w);
    *(ushort4*)(d+i) = o;
  }
}

// P0: cvt + transpose-cvt
__device__ __forceinline__ void dev_prep(const MegaArgs& P, int blk, int tid, char* smem)
{
  const int g = blk*256 + tid;
  cvt_range(P.iwV,  P.iwVb, 1048576, g);
  cvt_range(P.iwI,  P.iwIb, 1048576, g);
  cvt_range(P.cr_w, P.crwb, 131072,  g);
  cvt_range(P.rs_w, P.rswb, 131072,  g);
  float (*tile)[33] = (float(*)[33])smem;
  for (int t = blk; t < 2048; t += NBLK){        // exactly 4 iters per block
    int R, r0, c0; const float* src; u16* dst;
    if (t < 1024){
      const int zz = t>>9, rem = t&511;
      R = 512; r0 = (rem>>5)*32; c0 = (rem&31)*32;
      src = zz? P.owI : P.owV;  dst = zz? P.owTI : P.owTV;
    } else {
      const int tt = t-1024, img = tt>>8, rem = tt&255;
      R = 256; r0 = (rem>>5)*32; c0 = (rem&31)*32;
      src = (img<2 ? P.xV : P.xI) + (size_t)(img&1)*CIN*LQ;
      dst = P.xT + (size_t)img*LQ*CIN;
    }
    __syncthreads();
    {
      const int r = tid>>3, c = (tid&7)*4;
      const float4 v = *(const float4*)(src + (size_t)(r0+r)*1024 + c0 + c);
      tile[r][c]=v.x; tile[r][c+1]=v.y; tile[r][c+2]=v.z; tile[r][c+3]=v.w;
    }
    __syncthreads();
    {
      const int cl = tid>>3, rl = (tid&7)*4;
      ushort4 o;
      o.x = f2bf(tile[rl+0][cl]); o.y = f2bf(tile[rl+1][cl]);
      o.z = f2bf(tile[rl+2][cl]); o.w = f2bf(tile[rl+3][cl]);
      *(ushort4*)(dst + (size_t)(c0+cl)*R + r0 + rl) = o;
    }
  }
}

// P1: k1 conv-raise GEMM (all 512) + W2 pre-GEMM (blocks 0..31, second task)
__device__ __forceinline__ void dev_p1(const MegaArgs& P, int blk, int tid, char* smem)
{
  const int lane = tid&63, w = tid>>6;
  {
    const int m0 = (blk>>3)*64, n0 = (blk&7)*64;
    f32x4 acc[2][2];
    const f32x4 z = {0.f,0.f,0.f,0.f};
    #pragma unroll
    for (int mi=0;mi<2;++mi) for (int ni=0;ni<2;++ni) acc[mi][ni]=z;
    gemm_dbuf<64,64>(P.xT + (size_t)m0*CIN, P.crwb + (size_t)n0*CIN, CIN, (u16*)smem, acc, tid);
    #pragma unroll
    for (int mi=0;mi<2;++mi)
      #pragma unroll
      for (int ni=0;ni<2;++ni){
        const int n = n0 + (w&1)*32 + ni*16 + (lane&15);
        const float s = P.cr_g[n]*rsqrtf(P.cr_v[n]+EPSF);
        const float t = P.cr_b[n] - P.cr_m[n]*s;
        #pragma unroll
        for (int rr=0;rr<4;++rr){
          const int m = m0 + (w>>1)*32 + mi*16 + ((lane>>4)<<2) + rr;
          P.xr[(size_t)m*DM + n] = fmaxf(fmaf(acc[mi][ni][rr], s, t), 0.f);
        }
      }
  }
  if (blk < 32){
    __syncthreads();
    const int p = blk>>4, rem = blk&15;
    const int m0b = (rem>>3)*128, n0b = (rem&7)*128;
    f32x4 acc2[4][4];
    const f32x4 z = {0.f,0.f,0.f,0.f};
    #pragma unroll
    for (int mi=0;mi<4;++mi) for (int ni=0;ni<4;++ni) acc2[mi][ni]=z;
    gemm_dbuf<128,128>(P.rswb + (size_t)m0b*DM, (p? P.owTI : P.owTV) + (size_t)n0b*DM,
                       DM, (u16*)smem, acc2, tid);
    u16* __restrict__ orow = P.W2b + (size_t)p*256*1024;
    #pragma unroll
    for (int mi=0;mi<4;++mi)
      #pragma unroll
      for (int rr=0;rr<4;++rr){
        const int m = m0b + (w>>1)*64 + mi*16 + ((lane>>4)<<2) + rr;
        #pragma unroll
        for (int ni=0;ni<4;++ni){
          const int n = n0b + (w&1)*64 + ni*16 + (lane&15);
          orow[(size_t)m*1024 + n] = f2bf(acc2[mi][ni][rr]);
        }
      }
  }
}

// P2: fused LN -> bf16 xn + pool partials (64 blocks)
__device__ __forceinline__ void dev_k2f(const MegaArgs& P, int blk, int tid, char* smem)
{
  const int sl = blk&15, img = blk>>4, p = img>>1;
  const int l = tid&63, w = tid>>6;
  float* pw = (float*)smem;                    // [4][512]
  const float* lg = (p? P.lnIg : P.lnVg) + l*8;
  const float* lb = (p? P.lnIb : P.lnVb) + l*8;
  float g8[8], b8[8];
  *(float4*)&g8[0] = *(const float4*)lg;  *(float4*)&g8[4] = *(const float4*)(lg+4);
  *(float4*)&b8[0] = *(const float4*)lb;  *(float4*)&b8[4] = *(const float4*)(lb+4);
  float acc[8] = {};
  const int rbase = img*1024 + sl*64 + w*16;
  for (int r=0; r<16; ++r){
    const int row = rbase + r;
    const float* base = P.xr + (size_t)row*DM + l*8;
    float v[8];
    *(float4*)&v[0] = *(const float4*)(base);
    *(float4*)&v[4] = *(const float4*)(base+4);
    float s=0.f, q=0.f;
    #pragma unroll
    for (int j=0;j<8;++j){ s += v[j]; q += v[j]*v[j]; acc[j] += v[j]; }
    #pragma unroll
    for (int off=32; off; off>>=1){ s += __shfl_down(s,off); q += __shfl_down(q,off); }
    s = __shfl(s,0); q = __shfl(q,0);
    const float mean = s*(1.f/DM);
    const float rstd = rsqrtf(fmaxf(q*(1.f/DM) - mean*mean, 0.f)+EPSF);
    float y[8];
    #pragma unroll
    for (int j=0;j<8;++j) y[j] = (v[j]-mean)*rstd*g8[j] + b8[j];
    st8(P.xn + (size_t)row*DM + l*8, y);
  }
  #pragma unroll
  for (int j=0;j<8;++j) pw[w*512 + l*8+j] = acc[j];
  __syncthreads();
  for (int ch=tid; ch<DM; ch+=256)
    P.part[((size_t)img*16 + sl)*DM + ch] = pw[ch]+pw[512+ch]+pw[1024+ch]+pw[1536+ch];
}

__device__ __forceinline__ void dev_lambda(const MegaArgs& P, int img, int tid, char* smem)
{
  const int p = img>>1;
  const float* w1 = p? P.w1I : P.w1V;  const float* b1 = p? P.b1I : P.b1V;
  const float* w2 = p? P.w2I : P.w2V;  const float* b2 = p? P.b2I : P.b2V;
  float* pool = (float*)smem;          // [512]
  float* hb   = pool + DM;             // [128]
  for (int ch=tid; ch<DM; ch+=256){
    float s=0.f;
    #pragma unroll
    for (int sl=0; sl<16; ++sl) s += P.part[((size_t)img*16 + sl)*DM + ch];
    pool[ch] = s * (1.f/LQ);
  }
  __syncthreads();
  if (tid<128){
    float h = b1[tid];
    const float* wr = w1 + (size_t)tid*DM;
    for (int o=0;o<DM;o+=4){
      const float4 wv = *(const float4*)(wr+o);
      h += pool[o]*wv.x + pool[o+1]*wv.y + pool[o+2]*wv.z + pool[o+3]*wv.w;
    }
    hb[tid] = fmaxf(h,0.f);
  }
  __syncthreads();
  if (tid==0){
    float v = b2[0];
    for (int j=0;j<128;++j) v += hb[j]*w2[j];
    P.lam[img] = sigm(v);
  }
}

// P3: k3 in-proj GEMM (512 blocks)
__device__ __forceinline__ void dev_k3(const MegaArgs& P, int blk, int tid, char* smem)
{
  const int lane = tid&63, w = tid>>6;
  const int p = blk>>8, rem = blk&255;
  const int m0 = (rem>>4)*128, n0 = (rem&15)*128;
  const u16* A  = P.xn + (size_t)p*2048*DM;
  const u16* Bw = p? P.iwIb : P.iwVb;
  f32x4 acc[4][4];
  const f32x4 z = {0.f,0.f,0.f,0.f};
  #pragma unroll
  for (int mi=0;mi<4;++mi) for (int ni=0;ni<4;++ni) acc[mi][ni]=z;
  gemm_dbuf<128,128>(A + (size_t)m0*DM, Bw + (size_t)n0*DM, DM, (u16*)smem, acc, tid);
  u16* __restrict__ orow = P.xp + (size_t)p*2048*2048;
  #pragma unroll
  for (int mi=0;mi<4;++mi)
    #pragma unroll
    for (int rr=0;rr<4;++rr){
      const int m = m0 + (w>>1)*64 + mi*16 + ((lane>>4)<<2) + rr;
      #pragma unroll
      for (int ni=0;ni<4;++ni){
        const int n = n0 + (w&1)*64 + ni*16 + (lane&15);
        orow[(size_t)m*2048 + n] = f2bf(acc[mi][ni][rr]);
      }
    }
}

// P4: scan sweep 1 (raw chunk finals)
__device__ __forceinline__ void dev_k4s1(const MegaArgs& P, int blk, int tid, char* smem)
{
  const int p = blk>>8, rem = blk&255;
  const int c = rem>>3, rb = rem&7;
  const int row = rb*256 + tid;
  const int bb = rb>>2, il = (rb&3)*256, i = il + tid;
  u16* xs = (u16*)smem;                   // 16 KB
  {
    const u16* src = P.xp + ((size_t)(p*2048 + bb*1024 + c*TL))*2048 + il;
    const int r0 = tid>>5, cb = (tid&31)*8;
    #pragma unroll
    for (int rr=0; rr<TL; rr+=8)
      *(uint4*)(xs + (rr+r0)*256 + cb) = *(const uint4*)(src + (size_t)(rr+r0)*2048 + cb);
  }
  const float* Al = p? P.AI : P.AV;
  float a[16], uf[16], ub[16];
  #pragma unroll
  for (int s=0;s<16;s+=4){
    const float4 al = *(const float4*)(Al + (size_t)i*NS + s);
    a[s]=-expf(al.x); a[s+1]=-expf(al.y); a[s+2]=-expf(al.z); a[s+3]=-expf(al.w);
    uf[s]=0.f; uf[s+1]=0.f; uf[s+2]=0.f; uf[s+3]=0.f;
    ub[s]=0.f; ub[s+1]=0.f; ub[s+2]=0.f; ub[s+3]=0.f;
  }
  __syncthreads();
  #pragma unroll 4
  for (int tt=0; tt<TL; ++tt){
    const float xf = bf2f(xs[tt*256 + tid]);
    const float xb = bf2f(xs[(TL-1-tt)*256 + tid]);
    #pragma unroll
    for (int s=0;s<16;++s){
      uf[s] = fmaf(uf[s], a[s], xf);
      ub[s] = fmaf(ub[s], a[s], xb);
    }
  }
  u16* hpf = P.hfin + (((size_t)(p*2+0)*CH + c)*2048 + row)*NS;
  u16* hpb = P.hfin + (((size_t)(p*2+1)*CH + c)*2048 + row)*NS;
  st8(hpf, uf); st8(hpf+8, uf+8);
  st8(hpb, ub); st8(hpb+8, ub+8);
}

// P5: scan sweep 2 — in-register chunk prefix + register row-totals
__device__ __forceinline__ void dev_k4s2(const MegaArgs& P, int blk, int tid, char* smem)
{
  const int p = blk>>8, rem = blk&255;
  const int c = rem>>3, rb = rem&7;
  const int row = rb*256 + tid;
  const int bb = rb>>2, il = (rb&3)*256, i = il + tid;
  u16* xs = (u16*)smem;                   // 16 KB
  {
    const u16* src = P.xp + ((size_t)(p*2048 + bb*1024 + c*TL))*2048 + il;
    const int r0 = tid>>5, cb = (tid&31)*8;
    #pragma unroll
    for (int rr=0; rr<TL; rr+=8)
      *(uint4*)(xs + (rr+r0)*256 + cb) = *(const uint4*)(src + (size_t)(rr+r0)*2048 + cb);
  }
  const float* Al = p? P.AI : P.AV;
  const float* B0 = p? P.BI : P.BV;
  const float* B1 = p? P.BV : P.BI;
  const float* Cm = p? P.CI : P.CV;
  const float lm = P.lam[p*2+bb];
  float a[16], aT[16], dmix[16], uf[16], ub[16];
  #pragma unroll
  for (int s=0;s<16;s+=4){
    const float4 al = *(const float4*)(Al + (size_t)i*NS + s);
    const float4 b0 = *(const float4*)(B0 + (size_t)i*NS + s);
    const float4 b1 = *(const float4*)(B1 + (size_t)i*NS + s);
    const float4 cv = *(const float4*)(Cm + (size_t)i*NS + s);
    a[s]=-expf(al.x); a[s+1]=-expf(al.y); a[s+2]=-expf(al.z); a[s+3]=-expf(al.w);
    aT[s]  =expf((float)TL*al.x); aT[s+1]=expf((float)TL*al.y);
    aT[s+2]=expf((float)TL*al.z); aT[s+3]=expf((float)TL*al.w);
    dmix[s]  =(lm*b0.x+(1.f-lm)*b1.x)*cv.x;
    dmix[s+1]=(lm*b0.y+(1.f-lm)*b1.y)*cv.y;
    dmix[s+2]=(lm*b0.z+(1.f-lm)*b1.z)*cv.z;
    dmix[s+3]=(lm*b0.w+(1.f-lm)*b1.w)*cv.w;
    uf[s]=0.f; uf[s+1]=0.f; uf[s+2]=0.f; uf[s+3]=0.f;
    ub[s]=0.f; ub[s+1]=0.f; ub[s+2]=0.f; ub[s+3]=0.f;
  }
  const size_t cstride = (size_t)2048*NS;
  {
    const u16* hb = P.hfin + ((size_t)(p*2+0)*CH*2048 + row)*NS;
    if (c > 0){
      float fin[16];
      ld8(hb, fin); ld8(hb+8, fin+8);
      for (int j=1; j<c; ++j){
        float nx[16];
        ld8(hb + (size_t)j*cstride, nx); ld8(hb + (size_t)j*cstride + 8, nx+8);
        #pragma unroll
        for (int s=0;s<16;++s) uf[s] = fmaf(aT[s], uf[s], fin[s]);
        #pragma unroll
        for (int s=0;s<16;++s) fin[s] = nx[s];
      }
      #pragma unroll
      for (int s=0;s<16;++s) uf[s] = fmaf(aT[s], uf[s], fin[s]);
    }
  }
  {
    const u16* hb = P.hfin + ((size_t)(p*2+1)*CH*2048 + row)*NS;
    if (c < CH-1){
      float fin[16];
      ld8(hb + (size_t)(CH-1)*cstride, fin); ld8(hb + (size_t)(CH-1)*cstride + 8, fin+8);
      for (int j=CH-2; j>c; --j){
        float nx[16];
        ld8(hb + (size_t)j*cstride, nx); ld8(hb + (size_t)j*cstride + 8, nx+8);
        #pragma unroll
        for (int s=0;s<16;++s) ub[s] = fmaf(aT[s], ub[s], fin[s]);
        #pragma unroll
        for (int s=0;s<16;++s) fin[s] = nx[s];
      }
      #pragma unroll
      for (int s=0;s<16;++s) ub[s] = fmaf(aT[s], ub[s], fin[s]);
    }
  }
  __syncthreads();
  float tot[TL];
  #pragma unroll
  for (int tt=0; tt<TL; ++tt) tot[tt] = 0.f;
  #pragma unroll
  for (int tt=0; tt<TL; ++tt){
    const float xf = bf2f(xs[tt*256 + tid]);
    const float xb = bf2f(xs[(TL-1-tt)*256 + tid]);
    float yf0=0.f, yf1=0.f, yb0=0.f, yb1=0.f;
    #pragma unroll
    for (int s=0;s<16;s+=2){
      uf[s]   = fmaf(uf[s],   a[s],   xf);
      uf[s+1] = fmaf(uf[s+1], a[s+1], xf);
      ub[s]   = fmaf(ub[s],   a[s],   xb);
      ub[s+1] = fmaf(ub[s+1], a[s+1], xb);
      yf0 = fmaf(uf[s],   dmix[s],   yf0);
      yf1 = fmaf(uf[s+1], dmix[s+1], yf1);
      yb0 = fmaf(ub[s],   dmix[s],   yb0);
      yb1 = fmaf(ub[s+1], dmix[s+1], yb1);
    }
    tot[tt]      += (yf0+yf1);
    tot[TL-1-tt] += (yb0+yb1);
  }
  #pragma unroll
  for (int tt=0; tt<TL; ++tt){
    const size_t mrow = (size_t)(p*2048 + bb*1024 + c*TL + tt);
    const float g = bf2f(P.xp[mrow*2048 + DI + i]);
    P.comb[mrow*(size_t)DI + i] = f2bf(0.5f*g*sigm(g)*tot[tt]);
  }
}

// P6: fused out-proj GEMM + BN + residual (32x64 tiles, 512 blocks)
__device__ __forceinline__ void dev_k5(const MegaArgs& P, int blk, int tid, char* smem)
{
  const int lane = tid&63, w = tid>>6;
  const int p = blk>>8, rem = blk&255;
  const int m0 = (rem>>2)*32, n0 = (rem&3)*64;
  const u16* A = P.comb + (size_t)p*2048*DI;
  const u16* B = P.W2b + (size_t)p*256*1024;
  f32x4 acc[1][2];
  const f32x4 z = {0.f,0.f,0.f,0.f};
  acc[0][0]=z; acc[0][1]=z;
  gemm_dbuf<32,64>(A + (size_t)m0*DI, B + (size_t)n0*DI, DI, (u16*)smem, acc, tid);
  const int bb = m0>>10;
  const int img = p*2 + bb;
  const float* xres = (p? P.xI : P.xV) + (size_t)bb*CIN*LQ;
  float* obase = P.out + (size_t)img*CIN*LQ;
  #pragma unroll
  for (int ni=0;ni<2;++ni){
    const int q = n0 + (w&1)*32 + ni*16 + (lane&15);
    const float s = P.rs_g[q]*rsqrtf(P.rs_v[q]+EPSF);
    const float t = P.rs_b[q] - P.rs_m[q]*s;
    const int m = m0 + (w>>1)*16 + ((lane>>4)<<2);
    const int hw = m & 1023;
    const float4 xv = *(const float4*)(xres + (size_t)q*LQ + hw);
    float4 o;
    o.x = fmaf(acc[0][ni][0], s, t) + xv.x;
    o.y = fmaf(acc[0][ni][1], s, t) + xv.y;
    o.z = fmaf(acc[0][ni][2], s, t) + xv.z;
    o.w = fmaf(acc[0][ni][3], s, t) + xv.w;
    *(float4*)(obase + (size_t)q*LQ + hw) = o;
  }
}

// ==================== pipeline kernels ====================
__global__ __launch_bounds__(256) void kk_prep(MegaArgs P){
  __shared__ __align__(16) char smem[4352];
  dev_prep(P, blockIdx.x, threadIdx.x, smem);
}
__global__ __launch_bounds__(256) void kk_p1(MegaArgs P){
  __shared__ __align__(16) char smem[65536];      // 128x128 dbuf carve
  dev_p1(P, blockIdx.x, threadIdx.x, smem);
}
__global__ __launch_bounds__(256) void kk_p2(MegaArgs P){
  __shared__ __align__(16) char smem[8192];
  dev_k2f(P, blockIdx.x, threadIdx.x, smem);
}
__global__ __launch_bounds__(256) void kk_p3(MegaArgs P){
  __shared__ __align__(16) char smem[65536];
  dev_k3(P, blockIdx.x, threadIdx.x, smem);
}
__global__ __launch_bounds__(256) void kk_p4(MegaArgs P){
  __shared__ __align__(16) char smem[16384];
  if (blockIdx.x < NBLK) dev_k4s1(P, blockIdx.x, threadIdx.x, smem);
  else                   dev_lambda(P, blockIdx.x - NBLK, threadIdx.x, smem);
}
__global__ __launch_bounds__(256,2) void kk_p5(MegaArgs P){
  __shared__ __align__(16) char smem[16384];
  dev_k4s2(P, blockIdx.x, threadIdx.x, smem);
}
__global__ __launch_bounds__(256) void kk_p6(MegaArgs P){
  __shared__ __align__(16) char smem[24576];      // (32+64)*256
  dev_k5(P, blockIdx.x, threadIdx.x, smem);
}

extern "C" void kernel_launch(void* const* d_in, const int* in_sizes, int n_in,
                              void* d_out, int out_size, void* d_ws, size_t ws_size,
                              hipStream_t stream)
{
  char* ws = (char*)d_ws;
  MegaArgs P;
  P.cr_w = (const float*)d_in[0];  P.cr_g = (const float*)d_in[1];
  P.cr_b = (const float*)d_in[2];  P.cr_m = (const float*)d_in[3];
  P.cr_v = (const float*)d_in[4];
  P.rs_w = (const float*)d_in[5];  P.rs_g = (const float*)d_in[6];
  P.rs_b = (const float*)d_in[7];  P.rs_m = (const float*)d_in[8];
  P.rs_v = (const float*)d_in[9];
  P.lnVg = (const float*)d_in[10]; P.lnVb = (const float*)d_in[11];
  P.iwV  = (const float*)d_in[12]; P.AV   = (const float*)d_in[13];
  P.BV   = (const float*)d_in[14]; P.CV   = (const float*)d_in[15];
  P.owV  = (const float*)d_in[16];
  P.w1V  = (const float*)d_in[17]; P.b1V  = (const float*)d_in[18];
  P.w2V  = (const float*)d_in[19]; P.b2V  = (const float*)d_in[20];
  P.lnIg = (const float*)d_in[21]; P.lnIb = (const float*)d_in[22];
  P.iwI  = (const float*)d_in[23]; P.AI   = (const float*)d_in[24];
  P.BI   = (const float*)d_in[25]; P.CI   = (const float*)d_in[26];
  P.owI  = (const float*)d_in[27];
  P.w1I  = (const float*)d_in[28]; P.b1I  = (const float*)d_in[29];
  P.w2I  = (const float*)d_in[30]; P.b2I  = (const float*)d_in[31];
  P.xV   = (const float*)d_in[32]; P.xI   = (const float*)d_in[33];
  P.out  = (float*)d_out;
  // ws layout (~47.8 MB peak):
  P.xr   = (float*)(ws + 0);            // [4096][512] f32          8,388,608
  P.xn   = (u16*)  (ws + 8388608);      // [2][2048][512] bf16      4,194,304
  P.lam  = (float*)(ws + 12582912);     // [4] f32 (+pad)                 512
  P.iwVb = (u16*)  (ws + 12583424);     // [2048][512] bf16         2,097,152
  P.iwIb = (u16*)  (ws + 14680576);     // [2048][512] bf16         2,097,152
  P.owTV = (u16*)  (ws + 16777728);     // [1024][512] bf16         1,048,576
  P.owTI = (u16*)  (ws + 17826304);     // [1024][512] bf16         1,048,576
  P.rswb = (u16*)  (ws + 18874880);     // [256][512] bf16            262,144
  P.crwb = (u16*)  (ws + 19137024);     // [512][256] bf16            262,144
  P.xT   = (u16*)  (ws + 19399168);     // [4][1024][256] bf16      2,097,152
  P.W2b  = (u16*)  (ws + 21496320);     // [2][256][1024] bf16      1,048,576
  P.part = (float*)(ws + 22544896);     // [4][16][512] f32           131,072
  P.xp   = (u16*)  (ws + 22675968);     // [2][2048][2048] bf16    16,777,216
  P.comb = (u16*)  (ws + 39453184);     // [2][2048][1024] bf16     8,388,608
  P.hfin = (u16*)  (ws + 0);            // [4][32][2048][16] bf16   8,388,608 (aliases xr; xr dead after p2)

  kk_prep<<<dim3(NBLK),  dim3(256), 0, stream>>>(P);
  kk_p1  <<<dim3(NBLK),  dim3(256), 0, stream>>>(P);
  kk_p2  <<<dim3(64),    dim3(256), 0, stream>>>(P);
  kk_p3  <<<dim3(NBLK),  dim3(256), 0, stream>>>(P);
  kk_p4  <<<dim3(NBLK+4),dim3(256), 0, stream>>>(P);
  kk_p5  <<<dim3(NBLK),  dim3(256), 0, stream>>>(P);
  kk_p6  <<<dim3(NBLK),  dim3(256), 0, stream>>>(P);
}

// Round 12
// 107.741 us; speedup vs baseline: 4.2930x; 1.0180x over previous
//
#include <hip/hip_runtime.h>
#include <math.h>

typedef unsigned short u16;
typedef unsigned int   u32;
typedef __bf16 bf16x8 __attribute__((ext_vector_type(8)));
typedef float  f32x4  __attribute__((ext_vector_type(4)));

#define LQ   1024     // H*W
#define DM   512      // d_model
#define DI   1024     // d_inner
#define NS   16       // d_state
#define CIN  256
#define EPSF 1e-5f
#define CH   32       // scan chunks
#define TL   32       // chunk length (CH*TL == LQ)
#define NBLK 512

__device__ __forceinline__ float bf2f(u16 u){ return __uint_as_float(((u32)u)<<16); }
__device__ __forceinline__ u16 f2bf(float f){
  u32 x = __float_as_uint(f);
  x += 0x7fffu + ((x>>16)&1u);           // RNE
  return (u16)(x>>16);
}
__device__ __forceinline__ float sigm(float x){ return 1.f/(1.f+expf(-x)); }

__device__ __forceinline__ void ld8(const u16* p, float* f){
  const uint4 v = *(const uint4*)p;
  f[0]=bf2f((u16)v.x); f[1]=bf2f((u16)(v.x>>16));
  f[2]=bf2f((u16)v.y); f[3]=bf2f((u16)(v.y>>16));
  f[4]=bf2f((u16)v.z); f[5]=bf2f((u16)(v.z>>16));
  f[6]=bf2f((u16)v.w); f[7]=bf2f((u16)(v.w>>16));
}
__device__ __forceinline__ void st8(u16* p, const float* f){
  uint4 v;
  v.x = (u32)f2bf(f[0]) | ((u32)f2bf(f[1])<<16);
  v.y = (u32)f2bf(f[2]) | ((u32)f2bf(f[3])<<16);
  v.z = (u32)f2bf(f[4]) | ((u32)f2bf(f[5])<<16);
  v.w = (u32)f2bf(f[6]) | ((u32)f2bf(f[7])<<16);
  *(uint4*)p = v;
}

// ---- async global->LDS DMA: 16 B per lane, dest = uniform base + lane*16 ----
typedef const __attribute__((address_space(1))) u32* gas_t;
typedef __attribute__((address_space(3))) u32* las_t;
__device__ __forceinline__ void gld16(const void* g, void* l){
  __builtin_amdgcn_global_load_lds((gas_t)g, (las_t)l, 16, 0, 0);
}

// ---- double-buffered MFMA GEMM: stage(t+1) BEFORE compute(t), counted vmcnt ----
// LDS: linear [row][64] with XOR-swizzled chunk slots (linear gload_lds dest +
// inverse-swz global SOURCE + swz READ, same involution) -> conflict-free.
template<int TM, int TN>
__device__ __forceinline__ void gemm_dbuf(const u16* __restrict__ A, const u16* __restrict__ B,
                                          int K, u16* sm, f32x4 (&acc)[TM/32][TN/32], int tid)
{
  const int lane = tid&63, w = tid>>6;
  const int m_off = (w>>1)*(TM/2), n_off = (w&1)*(TN/2);
  const int lr = lane>>3, lp = lane&7, pos = lp ^ lr;
  u16* Asb[2] = { sm,            sm + TM*64 };
  u16* Bsb[2] = { sm + 2*TM*64,  sm + 2*TM*64 + TN*64 };
  const int NT = K>>6;
  constexpr int NV = TM/32 + TN/32;       // gld16s per wave per tile
  #pragma unroll
  for (int j=0;j<TM/32;++j){
    const int rb=(w*(TM/32)+j)*8;
    gld16(A + (size_t)(rb+lr)*K + (pos<<3), Asb[0] + rb*64);
  }
  #pragma unroll
  for (int j=0;j<TN/32;++j){
    const int rb=(w*(TN/32)+j)*8;
    gld16(B + (size_t)(rb+lr)*K + (pos<<3), Bsb[0] + rb*64);
  }
  for (int t=0;t<NT;++t){
    const int cur = t&1, nxt = cur^1;
    if (t+1 < NT){
      const int k0 = (t+1)<<6;
      #pragma unroll
      for (int j=0;j<TM/32;++j){
        const int rb=(w*(TM/32)+j)*8;
        gld16(A + (size_t)(rb+lr)*K + k0 + (pos<<3), Asb[nxt] + rb*64);
      }
      #pragma unroll
      for (int j=0;j<TN/32;++j){
        const int rb=(w*(TN/32)+j)*8;
        gld16(B + (size_t)(rb+lr)*K + k0 + (pos<<3), Bsb[nxt] + rb*64);
      }
      if constexpr (NV==8)      asm volatile("s_waitcnt vmcnt(8)" ::: "memory");
      else if constexpr (NV==4) asm volatile("s_waitcnt vmcnt(4)" ::: "memory");
      else                      asm volatile("s_waitcnt vmcnt(3)" ::: "memory");
    } else {
      asm volatile("s_waitcnt vmcnt(0)" ::: "memory");
    }
    __builtin_amdgcn_sched_barrier(0);
    __builtin_amdgcn_s_barrier();
    __builtin_amdgcn_sched_barrier(0);
    const u16* Ac = Asb[cur]; const u16* Bc = Bsb[cur];
    #pragma unroll
    for (int ks=0;ks<2;++ks){
      const int c = ks*4 + (lane>>4);
      bf16x8 af[TM/32], bb[TN/32];
      #pragma unroll
      for (int mi=0;mi<TM/32;++mi){
        const int R = m_off + mi*16 + (lane&15);
        af[mi] = *(const bf16x8*)(Ac + R*64 + ((c ^ (R&7))<<3));
      }
      #pragma unroll
      for (int ni=0;ni<TN/32;++ni){
        const int R = n_off + ni*16 + (lane&15);
        bb[ni] = *(const bf16x8*)(Bc + R*64 + ((c ^ (R&7))<<3));
      }
      #pragma unroll
      for (int mi=0;mi<TM/32;++mi)
        #pragma unroll
        for (int ni=0;ni<TN/32;++ni)
          acc[mi][ni] = __builtin_amdgcn_mfma_f32_16x16x32_bf16(af[mi], bb[ni], acc[mi][ni], 0,0,0);
    }
    __builtin_amdgcn_sched_barrier(0);
    __builtin_amdgcn_s_barrier();
  }
}

struct MegaArgs {
  const float *cr_w, *cr_g, *cr_b, *cr_m, *cr_v;
  const float *rs_w, *rs_g, *rs_b, *rs_m, *rs_v;
  const float *lnVg, *lnVb, *iwV, *AV, *BV, *CV, *owV;
  const float *w1V, *b1V, *w2V, *b2V;
  const float *lnIg, *lnIb, *iwI, *AI, *BI, *CI, *owI;
  const float *w1I, *b1I, *w2I, *b2I;
  const float *xV, *xI;
  float* out;
  float* xr; u16* xn; float* lam;
  u16 *iwVb, *iwIb, *owTV, *owTI, *rswb, *W2b;
  float* part; u16 *xp, *comb, *hfin;
};

__device__ __forceinline__ void cvt_range(const float* __restrict__ s, u16* __restrict__ d,
                                          int n, int g){
  for (int i = g*4; i < n; i += NBLK*256*4){
    const float4 v = *(const float4*)(s+i);
    ushort4 o; o.x=f2bf(v.x); o.y=f2bf(v.y); o.z=f2bf(v.z); o.w=f2bf(v.w);
    *(ushort4*)(d+i) = o;
  }
}

// prep (trimmed): cvt iwV/iwI/rsw + transpose-cvt ow.  Runs on blocks 512.. of p1big.
__device__ __forceinline__ void dev_prep2(const MegaArgs& P, int pblk, int tid, char* smem)
{
  const int g = pblk*256 + tid;
  cvt_range(P.iwV,  P.iwVb, 1048576, g);
  cvt_range(P.iwI,  P.iwIb, 1048576, g);
  cvt_range(P.rs_w, P.rswb, 131072,  g);
  float (*tile)[33] = (float(*)[33])smem;
  for (int t = pblk; t < 1024; t += 512){      // exactly 2 iters, uniform
    const int zz = t>>9, rem = t&511;
    const int r0 = (rem>>5)*32, c0 = (rem&31)*32;
    const float* src = zz? P.owI : P.owV;      // [512][1024]
    u16* dst = zz? P.owTI : P.owTV;            // [1024][512]
    __syncthreads();
    {
      const int r = tid>>3, c = (tid&7)*4;
      const float4 v = *(const float4*)(src + (size_t)(r0+r)*1024 + c0 + c);
      tile[r][c]=v.x; tile[r][c+1]=v.y; tile[r][c+2]=v.z; tile[r][c+3]=v.w;
    }
    __syncthreads();
    {
      const int cl = tid>>3, rl = (tid&7)*4;
      ushort4 o;
      o.x = f2bf(tile[rl+0][cl]); o.y = f2bf(tile[rl+1][cl]);
      o.z = f2bf(tile[rl+2][cl]); o.w = f2bf(tile[rl+3][cl]);
      *(ushort4*)(dst + (size_t)(c0+cl)*512 + r0 + rl) = o;
    }
  }
}

// k1 direct-from-f32: xr[m][n] = relu(bn( X^T . crw^T )), reg-staged bf16 tiles.
// A: X[c][hw] f32 (transposed read), B: crw[n][c] f32.  64x64 tile, K=256, single-buffer.
__device__ __forceinline__ void dev_k1f(const MegaArgs& P, int blk, int tid, char* smem)
{
  const int lane = tid&63, w = tid>>6;
  const int m0 = (blk>>3)*64, n0 = (blk&7)*64;
  const int img = m0>>10, hw0 = m0&1023;
  const float* __restrict__ Xp = (img<2? P.xV : P.xI) + (size_t)(img&1)*CIN*LQ;
  u16* As = (u16*)smem;                 // [64][64]
  u16* Bs = (u16*)(smem + 8192);
  const int m_off = (w>>1)*32, n_off = (w&1)*32;
  f32x4 acc[2][2];
  const f32x4 z = {0.f,0.f,0.f,0.f};
  #pragma unroll
  for (int mi=0;mi<2;++mi) for (int ni=0;ni<2;++ni) acc[mi][ni]=z;
  // A-stage decomposition: thread owns row r=tid&63, k's cb2..cb2+15 (2 chunks)
  const int ar = tid&63, cb2 = (tid>>6)*16, aq0 = (tid>>6)*2;
  // B-stage: thread owns row br=tid>>2, k's kb..kb+15 (2 chunks)
  const int br = tid>>2, kb = (tid&3)*16, bq0 = (tid&3)*2;
  for (int t=0;t<4;++t){
    const int k0 = t*64;
    float va[16], vb[16];
    #pragma unroll
    for (int j=0;j<16;++j)
      va[j] = Xp[(size_t)(k0+cb2+j)*LQ + hw0 + ar];          // coalesced over ar
    #pragma unroll
    for (int j=0;j<16;j+=4)
      *(float4*)&vb[j] = *(const float4*)(P.cr_w + (size_t)(n0+br)*CIN + k0 + kb + j);
    if (t) __syncthreads();             // prev MFMA reads done before overwrite
    st8(As + ar*64 + (((aq0+0)^(ar&7))<<3), va);
    st8(As + ar*64 + (((aq0+1)^(ar&7))<<3), va+8);
    st8(Bs + br*64 + (((bq0+0)^(br&7))<<3), vb);
    st8(Bs + br*64 + (((bq0+1)^(br&7))<<3), vb+8);
    __syncthreads();
    #pragma unroll
    for (int ks=0;ks<2;++ks){
      const int c = ks*4 + (lane>>4);
      bf16x8 af[2], bb[2];
      #pragma unroll
      for (int mi=0;mi<2;++mi){
        const int R = m_off + mi*16 + (lane&15);
        af[mi] = *(const bf16x8*)(As + R*64 + ((c ^ (R&7))<<3));
      }
      #pragma unroll
      for (int ni=0;ni<2;++ni){
        const int R = n_off + ni*16 + (lane&15);
        bb[ni] = *(const bf16x8*)(Bs + R*64 + ((c ^ (R&7))<<3));
      }
      #pragma unroll
      for (int mi=0;mi<2;++mi)
        #pragma unroll
        for (int ni=0;ni<2;++ni)
          acc[mi][ni] = __builtin_amdgcn_mfma_f32_16x16x32_bf16(af[mi], bb[ni], acc[mi][ni], 0,0,0);
    }
  }
  #pragma unroll
  for (int mi=0;mi<2;++mi)
    #pragma unroll
    for (int ni=0;ni<2;++ni){
      const int n = n0 + n_off + ni*16 + (lane&15);
      const float s = P.cr_g[n]*rsqrtf(P.cr_v[n]+EPSF);
      const float t = P.cr_b[n] - P.cr_m[n]*s;
      #pragma unroll
      for (int rr=0;rr<4;++rr){
        const int m = m0 + m_off + mi*16 + ((lane>>4)<<2) + rr;
        P.xr[(size_t)m*DM + n] = fmaxf(fmaf(acc[mi][ni][rr], s, t), 0.f);
      }
    }
}

// W2 pre-GEMM (32 blocks): W2[p][q][kk] = sum_n rsw[q][n]*ow_p[n][kk]
__device__ __forceinline__ void dev_w2(const MegaArgs& P, int blk, int tid, char* smem)
{
  const int lane = tid&63, w = tid>>6;
  const int p = blk>>4, rem = blk&15;
  const int m0b = (rem>>3)*128, n0b = (rem&7)*128;
  f32x4 acc2[4][4];
  const f32x4 z = {0.f,0.f,0.f,0.f};
  #pragma unroll
  for (int mi=0;mi<4;++mi) for (int ni=0;ni<4;++ni) acc2[mi][ni]=z;
  gemm_dbuf<128,128>(P.rswb + (size_t)m0b*DM, (p? P.owTI : P.owTV) + (size_t)n0b*DM,
                     DM, (u16*)smem, acc2, tid);
  u16* __restrict__ orow = P.W2b + (size_t)p*256*1024;
  #pragma unroll
  for (int mi=0;mi<4;++mi)
    #pragma unroll
    for (int rr=0;rr<4;++rr){
      const int m = m0b + (w>>1)*64 + mi*16 + ((lane>>4)<<2) + rr;
      #pragma unroll
      for (int ni=0;ni<4;++ni){
        const int n = n0b + (w&1)*64 + ni*16 + (lane&15);
        orow[(size_t)m*1024 + n] = f2bf(acc2[mi][ni][rr]);
      }
    }
}

// P2: fused LN -> bf16 xn + pool partials (64 blocks)
__device__ __forceinline__ void dev_k2f(const MegaArgs& P, int blk, int tid, char* smem)
{
  const int sl = blk&15, img = blk>>4, p = img>>1;
  const int l = tid&63, w = tid>>6;
  float* pw = (float*)smem;                    // [4][512]
  const float* lg = (p? P.lnIg : P.lnVg) + l*8;
  const float* lb = (p? P.lnIb : P.lnVb) + l*8;
  float g8[8], b8[8];
  *(float4*)&g8[0] = *(const float4*)lg;  *(float4*)&g8[4] = *(const float4*)(lg+4);
  *(float4*)&b8[0] = *(const float4*)lb;  *(float4*)&b8[4] = *(const float4*)(lb+4);
  float acc[8] = {};
  const int rbase = img*1024 + sl*64 + w*16;
  for (int r=0; r<16; ++r){
    const int row = rbase + r;
    const float* base = P.xr + (size_t)row*DM + l*8;
    float v[8];
    *(float4*)&v[0] = *(const float4*)(base);
    *(float4*)&v[4] = *(const float4*)(base+4);
    float s=0.f, q=0.f;
    #pragma unroll
    for (int j=0;j<8;++j){ s += v[j]; q += v[j]*v[j]; acc[j] += v[j]; }
    #pragma unroll
    for (int off=32; off; off>>=1){ s += __shfl_down(s,off); q += __shfl_down(q,off); }
    s = __shfl(s,0); q = __shfl(q,0);
    const float mean = s*(1.f/DM);
    const float rstd = rsqrtf(fmaxf(q*(1.f/DM) - mean*mean, 0.f)+EPSF);
    float y[8];
    #pragma unroll
    for (int j=0;j<8;++j) y[j] = (v[j]-mean)*rstd*g8[j] + b8[j];
    st8(P.xn + (size_t)row*DM + l*8, y);
  }
  #pragma unroll
  for (int j=0;j<8;++j) pw[w*512 + l*8+j] = acc[j];
  __syncthreads();
  for (int ch=tid; ch<DM; ch+=256)
    P.part[((size_t)img*16 + sl)*DM + ch] = pw[ch]+pw[512+ch]+pw[1024+ch]+pw[1536+ch];
}

__device__ __forceinline__ void dev_lambda(const MegaArgs& P, int img, int tid, char* smem)
{
  const int p = img>>1;
  const float* w1 = p? P.w1I : P.w1V;  const float* b1 = p? P.b1I : P.b1V;
  const float* w2 = p? P.w2I : P.w2V;  const float* b2 = p? P.b2I : P.b2V;
  float* pool = (float*)smem;          // [512]
  float* hb   = pool + DM;             // [128]
  for (int ch=tid; ch<DM; ch+=256){
    float s=0.f;
    #pragma unroll
    for (int sl=0; sl<16; ++sl) s += P.part[((size_t)img*16 + sl)*DM + ch];
    pool[ch] = s * (1.f/LQ);
  }
  __syncthreads();
  if (tid<128){
    float h = b1[tid];
    const float* wr = w1 + (size_t)tid*DM;
    for (int o=0;o<DM;o+=4){
      const float4 wv = *(const float4*)(wr+o);
      h += pool[o]*wv.x + pool[o+1]*wv.y + pool[o+2]*wv.z + pool[o+3]*wv.w;
    }
    hb[tid] = fmaxf(h,0.f);
  }
  __syncthreads();
  if (tid==0){
    float v = b2[0];
    for (int j=0;j<128;++j) v += hb[j]*w2[j];
    P.lam[img] = sigm(v);
  }
}

// P3: k3 in-proj GEMM (512 blocks). Gate half (n0>=DI) stores 0.5*silu pre-applied.
__device__ __forceinline__ void dev_k3(const MegaArgs& P, int blk, int tid, char* smem)
{
  const int lane = tid&63, w = tid>>6;
  const int p = blk>>8, rem = blk&255;
  const int m0 = (rem>>4)*128, n0 = (rem&15)*128;
  const bool isGate = (n0 >= DI);
  const u16* A  = P.xn + (size_t)p*2048*DM;
  const u16* Bw = p? P.iwIb : P.iwVb;
  f32x4 acc[4][4];
  const f32x4 z = {0.f,0.f,0.f,0.f};
  #pragma unroll
  for (int mi=0;mi<4;++mi) for (int ni=0;ni<4;++ni) acc[mi][ni]=z;
  gemm_dbuf<128,128>(A + (size_t)m0*DM, Bw + (size_t)n0*DM, DM, (u16*)smem, acc, tid);
  u16* __restrict__ orow = P.xp + (size_t)p*2048*2048;
  #pragma unroll
  for (int mi=0;mi<4;++mi)
    #pragma unroll
    for (int rr=0;rr<4;++rr){
      const int m = m0 + (w>>1)*64 + mi*16 + ((lane>>4)<<2) + rr;
      #pragma unroll
      for (int ni=0;ni<4;++ni){
        const int n = n0 + (w&1)*64 + ni*16 + (lane&15);
        float v = acc[mi][ni][rr];
        if (isGate) v = 0.5f*v*sigm(v);
        orow[(size_t)m*2048 + n] = f2bf(v);
      }
    }
}

// P4: scan sweep 1 (raw chunk finals)
__device__ __forceinline__ void dev_k4s1(const MegaArgs& P, int blk, int tid, char* smem)
{
  const int p = blk>>8, rem = blk&255;
  const int c = rem>>3, rb = rem&7;
  const int row = rb*256 + tid;
  const int bb = rb>>2, il = (rb&3)*256, i = il + tid;
  u16* xs = (u16*)smem;                   // 16 KB
  {
    const u16* src = P.xp + ((size_t)(p*2048 + bb*1024 + c*TL))*2048 + il;
    const int r0 = tid>>5, cb = (tid&31)*8;
    #pragma unroll
    for (int rr=0; rr<TL; rr+=8)
      *(uint4*)(xs + (rr+r0)*256 + cb) = *(const uint4*)(src + (size_t)(rr+r0)*2048 + cb);
  }
  const float* Al = p? P.AI : P.AV;
  float a[16], uf[16], ub[16];
  #pragma unroll
  for (int s=0;s<16;s+=4){
    const float4 al = *(const float4*)(Al + (size_t)i*NS + s);
    a[s]=-expf(al.x); a[s+1]=-expf(al.y); a[s+2]=-expf(al.z); a[s+3]=-expf(al.w);
    uf[s]=0.f; uf[s+1]=0.f; uf[s+2]=0.f; uf[s+3]=0.f;
    ub[s]=0.f; ub[s+1]=0.f; ub[s+2]=0.f; ub[s+3]=0.f;
  }
  __syncthreads();
  #pragma unroll 4
  for (int tt=0; tt<TL; ++tt){
    const float xf = bf2f(xs[tt*256 + tid]);
    const float xb = bf2f(xs[(TL-1-tt)*256 + tid]);
    #pragma unroll
    for (int s=0;s<16;++s){
      uf[s] = fmaf(uf[s], a[s], xf);
      ub[s] = fmaf(ub[s], a[s], xb);
    }
  }
  u16* hpf = P.hfin + (((size_t)(p*2+0)*CH + c)*2048 + row)*NS;
  u16* hpb = P.hfin + (((size_t)(p*2+1)*CH + c)*2048 + row)*NS;
  st8(hpf, uf); st8(hpf+8, uf+8);
  st8(hpb, ub); st8(hpb+8, ub+8);
}

// P5: scan sweep 2 — in-register chunk prefix + register row-totals
__device__ __forceinline__ void dev_k4s2(const MegaArgs& P, int blk, int tid, char* smem)
{
  const int p = blk>>8, rem = blk&255;
  const int c = rem>>3, rb = rem&7;
  const int row = rb*256 + tid;
  const int bb = rb>>2, il = (rb&3)*256, i = il + tid;
  u16* xs = (u16*)smem;                   // 16 KB
  {
    const u16* src = P.xp + ((size_t)(p*2048 + bb*1024 + c*TL))*2048 + il;
    const int r0 = tid>>5, cb = (tid&31)*8;
    #pragma unroll
    for (int rr=0; rr<TL; rr+=8)
      *(uint4*)(xs + (rr+r0)*256 + cb) = *(const uint4*)(src + (size_t)(rr+r0)*2048 + cb);
  }
  const float* Al = p? P.AI : P.AV;
  const float* B0 = p? P.BI : P.BV;
  const float* B1 = p? P.BV : P.BI;
  const float* Cm = p? P.CI : P.CV;
  const float lm = P.lam[p*2+bb];
  float a[16], aT[16], dmix[16], uf[16], ub[16];
  #pragma unroll
  for (int s=0;s<16;s+=4){
    const float4 al = *(const float4*)(Al + (size_t)i*NS + s);
    const float4 b0 = *(const float4*)(B0 + (size_t)i*NS + s);
    const float4 b1 = *(const float4*)(B1 + (size_t)i*NS + s);
    const float4 cv = *(const float4*)(Cm + (size_t)i*NS + s);
    a[s]=-expf(al.x); a[s+1]=-expf(al.y); a[s+2]=-expf(al.z); a[s+3]=-expf(al.w);
    aT[s]  =expf((float)TL*al.x); aT[s+1]=expf((float)TL*al.y);
    aT[s+2]=expf((float)TL*al.z); aT[s+3]=expf((float)TL*al.w);
    dmix[s]  =(lm*b0.x+(1.f-lm)*b1.x)*cv.x;
    dmix[s+1]=(lm*b0.y+(1.f-lm)*b1.y)*cv.y;
    dmix[s+2]=(lm*b0.z+(1.f-lm)*b1.z)*cv.z;
    dmix[s+3]=(lm*b0.w+(1.f-lm)*b1.w)*cv.w;
    uf[s]=0.f; uf[s+1]=0.f; uf[s+2]=0.f; uf[s+3]=0.f;
    ub[s]=0.f; ub[s+1]=0.f; ub[s+2]=0.f; ub[s+3]=0.f;
  }
  const size_t cstride = (size_t)2048*NS;
  {
    const u16* hb = P.hfin + ((size_t)(p*2+0)*CH*2048 + row)*NS;
    if (c > 0){
      float fin[16];
      ld8(hb, fin); ld8(hb+8, fin+8);
      for (int j=1; j<c; ++j){
        float nx[16];
        ld8(hb + (size_t)j*cstride, nx); ld8(hb + (size_t)j*cstride + 8, nx+8);
        #pragma unroll
        for (int s=0;s<16;++s) uf[s] = fmaf(aT[s], uf[s], fin[s]);
        #pragma unroll
        for (int s=0;s<16;++s) fin[s] = nx[s];
      }
      #pragma unroll
      for (int s=0;s<16;++s) uf[s] = fmaf(aT[s], uf[s], fin[s]);
    }
  }
  {
    const u16* hb = P.hfin + ((size_t)(p*2+1)*CH*2048 + row)*NS;
    if (c < CH-1){
      float fin[16];
      ld8(hb + (size_t)(CH-1)*cstride, fin); ld8(hb + (size_t)(CH-1)*cstride + 8, fin+8);
      for (int j=CH-2; j>c; --j){
        float nx[16];
        ld8(hb + (size_t)j*cstride, nx); ld8(hb + (size_t)j*cstride + 8, nx+8);
        #pragma unroll
        for (int s=0;s<16;++s) ub[s] = fmaf(aT[s], ub[s], fin[s]);
        #pragma unroll
        for (int s=0;s<16;++s) fin[s] = nx[s];
      }
      #pragma unroll
      for (int s=0;s<16;++s) ub[s] = fmaf(aT[s], ub[s], fin[s]);
    }
  }
  __syncthreads();
  float tot[TL];
  #pragma unroll
  for (int tt=0; tt<TL; ++tt) tot[tt] = 0.f;
  #pragma unroll
  for (int tt=0; tt<TL; ++tt){
    const float xf = bf2f(xs[tt*256 + tid]);
    const float xb = bf2f(xs[(TL-1-tt)*256 + tid]);
    float yf0=0.f, yf1=0.f, yb0=0.f, yb1=0.f;
    #pragma unroll
    for (int s=0;s<16;s+=2){
      uf[s]   = fmaf(uf[s],   a[s],   xf);
      uf[s+1] = fmaf(uf[s+1], a[s+1], xf);
      ub[s]   = fmaf(ub[s],   a[s],   xb);
      ub[s+1] = fmaf(ub[s+1], a[s+1], xb);
      yf0 = fmaf(uf[s],   dmix[s],   yf0);
      yf1 = fmaf(uf[s+1], dmix[s+1], yf1);
      yb0 = fmaf(ub[s],   dmix[s],   yb0);
      yb1 = fmaf(ub[s+1], dmix[s+1], yb1);
    }
    tot[tt]      += (yf0+yf1);
    tot[TL-1-tt] += (yb0+yb1);
  }
  // epilogue: gate half of xp already holds 0.5*silu(g)
  #pragma unroll
  for (int tt=0; tt<TL; ++tt){
    const size_t mrow = (size_t)(p*2048 + bb*1024 + c*TL + tt);
    const float sg = bf2f(P.xp[mrow*2048 + DI + i]);
    P.comb[mrow*(size_t)DI + i] = f2bf(sg*tot[tt]);
  }
}

// P6: fused out-proj GEMM + BN + residual (32x64 tiles, 512 blocks)
__device__ __forceinline__ void dev_k5(const MegaArgs& P, int blk, int tid, char* smem)
{
  const int lane = tid&63, w = tid>>6;
  const int p = blk>>8, rem = blk&255;
  const int m0 = (rem>>2)*32, n0 = (rem&3)*64;
  const u16* A = P.comb + (size_t)p*2048*DI;
  const u16* B = P.W2b + (size_t)p*256*1024;
  f32x4 acc[1][2];
  const f32x4 z = {0.f,0.f,0.f,0.f};
  acc[0][0]=z; acc[0][1]=z;
  gemm_dbuf<32,64>(A + (size_t)m0*DI, B + (size_t)n0*DI, DI, (u16*)smem, acc, tid);
  const int bb = m0>>10;
  const int img = p*2 + bb;
  const float* xres = (p? P.xI : P.xV) + (size_t)bb*CIN*LQ;
  float* obase = P.out + (size_t)img*CIN*LQ;
  #pragma unroll
  for (int ni=0;ni<2;++ni){
    const int q = n0 + (w&1)*32 + ni*16 + (lane&15);
    const float s = P.rs_g[q]*rsqrtf(P.rs_v[q]+EPSF);
    const float t = P.rs_b[q] - P.rs_m[q]*s;
    const int m = m0 + (w>>1)*16 + ((lane>>4)<<2);
    const int hw = m & 1023;
    const float4 xv = *(const float4*)(xres + (size_t)q*LQ + hw);
    float4 o;
    o.x = fmaf(acc[0][ni][0], s, t) + xv.x;
    o.y = fmaf(acc[0][ni][1], s, t) + xv.y;
    o.z = fmaf(acc[0][ni][2], s, t) + xv.z;
    o.w = fmaf(acc[0][ni][3], s, t) + xv.w;
    *(float4*)(obase + (size_t)q*LQ + hw) = o;
  }
}

// ==================== pipeline kernels (6 launches) ====================
__global__ __launch_bounds__(256) void kk_p1big(MegaArgs P){
  __shared__ __align__(16) char smem[16384];
  if (blockIdx.x < 512) dev_k1f(P, blockIdx.x, threadIdx.x, smem);
  else                  dev_prep2(P, blockIdx.x - 512, threadIdx.x, smem);
}
__global__ __launch_bounds__(256) void kk_p2(MegaArgs P){
  __shared__ __align__(16) char smem[65536];
  if (blockIdx.x < 64) dev_k2f(P, blockIdx.x, threadIdx.x, smem);
  else                 dev_w2(P, blockIdx.x - 64, threadIdx.x, smem);
}
__global__ __launch_bounds__(256) void kk_p3(MegaArgs P){
  __shared__ __align__(16) char smem[65536];
  dev_k3(P, blockIdx.x, threadIdx.x, smem);
}
__global__ __launch_bounds__(256) void kk_p4(MegaArgs P){
  __shared__ __align__(16) char smem[16384];
  if (blockIdx.x < NBLK) dev_k4s1(P, blockIdx.x, threadIdx.x, smem);
  else                   dev_lambda(P, blockIdx.x - NBLK, threadIdx.x, smem);
}
__global__ __launch_bounds__(256,2) void kk_p5(MegaArgs P){
  __shared__ __align__(16) char smem[16384];
  dev_k4s2(P, blockIdx.x, threadIdx.x, smem);
}
__global__ __launch_bounds__(256) void kk_p6(MegaArgs P){
  __shared__ __align__(16) char smem[24576];      // (32+64)*256
  dev_k5(P, blockIdx.x, threadIdx.x, smem);
}

extern "C" void kernel_launch(void* const* d_in, const int* in_sizes, int n_in,
                              void* d_out, int out_size, void* d_ws, size_t ws_size,
                              hipStream_t stream)
{
  char* ws = (char*)d_ws;
  MegaArgs P;
  P.cr_w = (const float*)d_in[0];  P.cr_g = (const float*)d_in[1];
  P.cr_b = (const float*)d_in[2];  P.cr_m = (const float*)d_in[3];
  P.cr_v = (const float*)d_in[4];
  P.rs_w = (const float*)d_in[5];  P.rs_g = (const float*)d_in[6];
  P.rs_b = (const float*)d_in[7];  P.rs_m = (const float*)d_in[8];
  P.rs_v = (const float*)d_in[9];
  P.lnVg = (const float*)d_in[10]; P.lnVb = (const float*)d_in[11];
  P.iwV  = (const float*)d_in[12]; P.AV   = (const float*)d_in[13];
  P.BV   = (const float*)d_in[14]; P.CV   = (const float*)d_in[15];
  P.owV  = (const float*)d_in[16];
  P.w1V  = (const float*)d_in[17]; P.b1V  = (const float*)d_in[18];
  P.w2V  = (const float*)d_in[19]; P.b2V  = (const float*)d_in[20];
  P.lnIg = (const float*)d_in[21]; P.lnIb = (const float*)d_in[22];
  P.iwI  = (const float*)d_in[23]; P.AI   = (const float*)d_in[24];
  P.BI   = (const float*)d_in[25]; P.CI   = (const float*)d_in[26];
  P.owI  = (const float*)d_in[27];
  P.w1I  = (const float*)d_in[28]; P.b1I  = (const float*)d_in[29];
  P.w2I  = (const float*)d_in[30]; P.b2I  = (const float*)d_in[31];
  P.xV   = (const float*)d_in[32]; P.xI   = (const float*)d_in[33];
  P.out  = (float*)d_out;
  // ws layout (~47.8 MB peak):
  P.xr   = (float*)(ws + 0);            // [4096][512] f32          8,388,608
  P.xn   = (u16*)  (ws + 8388608);      // [2][2048][512] bf16      4,194,304
  P.lam  = (float*)(ws + 12582912);     // [4] f32 (+pad)                 512
  P.iwVb = (u16*)  (ws + 12583424);     // [2048][512] bf16         2,097,152
  P.iwIb = (u16*)  (ws + 14680576);     // [2048][512] bf16         2,097,152
  P.owTV = (u16*)  (ws + 16777728);     // [1024][512] bf16         1,048,576
  P.owTI = (u16*)  (ws + 17826304);     // [1024][512] bf16         1,048,576
  P.rswb = (u16*)  (ws + 18874880);     // [256][512] bf16            262,144
  P.W2b  = (u16*)  (ws + 21496320);     // [2][256][1024] bf16      1,048,576
  P.part = (float*)(ws + 22544896);     // [4][16][512] f32           131,072
  P.xp   = (u16*)  (ws + 22675968);     // [2][2048][2048] bf16    16,777,216
  P.comb = (u16*)  (ws + 39453184);     // [2][2048][1024] bf16     8,388,608
  P.hfin = (u16*)  (ws + 0);            // [4][32][2048][16] bf16   8,388,608 (aliases xr; xr dead after p2)

  kk_p1big<<<dim3(1024),  dim3(256), 0, stream>>>(P);
  kk_p2   <<<dim3(96),    dim3(256), 0, stream>>>(P);
  kk_p3   <<<dim3(NBLK),  dim3(256), 0, stream>>>(P);
  kk_p4   <<<dim3(NBLK+4),dim3(256), 0, stream>>>(P);
  kk_p5   <<<dim3(NBLK),  dim3(256), 0, stream>>>(P);
  kk_p6   <<<dim3(NBLK),  dim3(256), 0, stream>>>(P);
}

// Round 13
// 107.194 us; speedup vs baseline: 4.3149x; 1.0051x over previous
//
#include <hip/hip_runtime.h>
#include <math.h>

typedef unsigned short u16;
typedef unsigned int   u32;
typedef __bf16 bf16x8 __attribute__((ext_vector_type(8)));
typedef float  f32x4  __attribute__((ext_vector_type(4)));

#define LQ   1024     // H*W
#define DM   512      // d_model
#define DI   1024     // d_inner
#define NS   16       // d_state
#define CIN  256
#define EPSF 1e-5f
#define CH   32       // scan chunks
#define TL   32       // chunk length (CH*TL == LQ)
#define NBLK 512

__device__ __forceinline__ float bf2f(u16 u){ return __uint_as_float(((u32)u)<<16); }
__device__ __forceinline__ u16 f2bf(float f){
  u32 x = __float_as_uint(f);
  x += 0x7fffu + ((x>>16)&1u);           // RNE
  return (u16)(x>>16);
}
__device__ __forceinline__ float sigm(float x){ return 1.f/(1.f+expf(-x)); }

// XCD-aware bijective swizzle for 512-block grids (512 % 8 == 0): XCD k gets
// contiguous logical tiles [k*64,(k+1)*64) since HW assigns block b -> XCD b%8.
__device__ __forceinline__ int swz512(int b){ return (b&7)*64 + (b>>3); }

__device__ __forceinline__ void ld8(const u16* p, float* f){
  const uint4 v = *(const uint4*)p;
  f[0]=bf2f((u16)v.x); f[1]=bf2f((u16)(v.x>>16));
  f[2]=bf2f((u16)v.y); f[3]=bf2f((u16)(v.y>>16));
  f[4]=bf2f((u16)v.z); f[5]=bf2f((u16)(v.z>>16));
  f[6]=bf2f((u16)v.w); f[7]=bf2f((u16)(v.w>>16));
}
__device__ __forceinline__ void st8(u16* p, const float* f){
  uint4 v;
  v.x = (u32)f2bf(f[0]) | ((u32)f2bf(f[1])<<16);
  v.y = (u32)f2bf(f[2]) | ((u32)f2bf(f[3])<<16);
  v.z = (u32)f2bf(f[4]) | ((u32)f2bf(f[5])<<16);
  v.w = (u32)f2bf(f[6]) | ((u32)f2bf(f[7])<<16);
  *(uint4*)p = v;
}

// ---- async global->LDS DMA: 16 B per lane, dest = uniform base + lane*16 ----
typedef const __attribute__((address_space(1))) u32* gas_t;
typedef __attribute__((address_space(3))) u32* las_t;
__device__ __forceinline__ void gld16(const void* g, void* l){
  __builtin_amdgcn_global_load_lds((gas_t)g, (las_t)l, 16, 0, 0);
}

// ---- double-buffered MFMA GEMM: stage(t+1) BEFORE compute(t), counted vmcnt ----
// LDS: linear [row][64] with XOR-swizzled chunk slots (linear gload_lds dest +
// inverse-swz global SOURCE + swz READ, same involution) -> conflict-free.
template<int TM, int TN>
__device__ __forceinline__ void gemm_dbuf(const u16* __restrict__ A, const u16* __restrict__ B,
                                          int K, u16* sm, f32x4 (&acc)[TM/32][TN/32], int tid)
{
  const int lane = tid&63, w = tid>>6;
  const int m_off = (w>>1)*(TM/2), n_off = (w&1)*(TN/2);
  const int lr = lane>>3, lp = lane&7, pos = lp ^ lr;
  u16* Asb[2] = { sm,            sm + TM*64 };
  u16* Bsb[2] = { sm + 2*TM*64,  sm + 2*TM*64 + TN*64 };
  const int NT = K>>6;
  constexpr int NV = TM/32 + TN/32;       // gld16s per wave per tile
  #pragma unroll
  for (int j=0;j<TM/32;++j){
    const int rb=(w*(TM/32)+j)*8;
    gld16(A + (size_t)(rb+lr)*K + (pos<<3), Asb[0] + rb*64);
  }
  #pragma unroll
  for (int j=0;j<TN/32;++j){
    const int rb=(w*(TN/32)+j)*8;
    gld16(B + (size_t)(rb+lr)*K + (pos<<3), Bsb[0] + rb*64);
  }
  for (int t=0;t<NT;++t){
    const int cur = t&1, nxt = cur^1;
    if (t+1 < NT){
      const int k0 = (t+1)<<6;
      #pragma unroll
      for (int j=0;j<TM/32;++j){
        const int rb=(w*(TM/32)+j)*8;
        gld16(A + (size_t)(rb+lr)*K + k0 + (pos<<3), Asb[nxt] + rb*64);
      }
      #pragma unroll
      for (int j=0;j<TN/32;++j){
        const int rb=(w*(TN/32)+j)*8;
        gld16(B + (size_t)(rb+lr)*K + k0 + (pos<<3), Bsb[nxt] + rb*64);
      }
      if constexpr (NV==8)      asm volatile("s_waitcnt vmcnt(8)" ::: "memory");
      else if constexpr (NV==4) asm volatile("s_waitcnt vmcnt(4)" ::: "memory");
      else                      asm volatile("s_waitcnt vmcnt(3)" ::: "memory");
    } else {
      asm volatile("s_waitcnt vmcnt(0)" ::: "memory");
    }
    __builtin_amdgcn_sched_barrier(0);
    __builtin_amdgcn_s_barrier();
    __builtin_amdgcn_sched_barrier(0);
    const u16* Ac = Asb[cur]; const u16* Bc = Bsb[cur];
    #pragma unroll
    for (int ks=0;ks<2;++ks){
      const int c = ks*4 + (lane>>4);
      bf16x8 af[TM/32], bb[TN/32];
      #pragma unroll
      for (int mi=0;mi<TM/32;++mi){
        const int R = m_off + mi*16 + (lane&15);
        af[mi] = *(const bf16x8*)(Ac + R*64 + ((c ^ (R&7))<<3));
      }
      #pragma unroll
      for (int ni=0;ni<TN/32;++ni){
        const int R = n_off + ni*16 + (lane&15);
        bb[ni] = *(const bf16x8*)(Bc + R*64 + ((c ^ (R&7))<<3));
      }
      #pragma unroll
      for (int mi=0;mi<TM/32;++mi)
        #pragma unroll
        for (int ni=0;ni<TN/32;++ni)
          acc[mi][ni] = __builtin_amdgcn_mfma_f32_16x16x32_bf16(af[mi], bb[ni], acc[mi][ni], 0,0,0);
    }
    __builtin_amdgcn_sched_barrier(0);
    __builtin_amdgcn_s_barrier();
  }
}

struct MegaArgs {
  const float *cr_w, *cr_g, *cr_b, *cr_m, *cr_v;
  const float *rs_w, *rs_g, *rs_b, *rs_m, *rs_v;
  const float *lnVg, *lnVb, *iwV, *AV, *BV, *CV, *owV;
  const float *w1V, *b1V, *w2V, *b2V;
  const float *lnIg, *lnIb, *iwI, *AI, *BI, *CI, *owI;
  const float *w1I, *b1I, *w2I, *b2I;
  const float *xV, *xI;
  float* out;
  float* xr; u16* xn; float* lam;
  u16 *iwVb, *iwIb, *owTV, *owTI, *rswb, *W2b;
  float* part; u16 *xp, *comb, *hfin;
};

__device__ __forceinline__ void cvt_range(const float* __restrict__ s, u16* __restrict__ d,
                                          int n, int g){
  for (int i = g*4; i < n; i += NBLK*256*4){
    const float4 v = *(const float4*)(s+i);
    ushort4 o; o.x=f2bf(v.x); o.y=f2bf(v.y); o.z=f2bf(v.z); o.w=f2bf(v.w);
    *(ushort4*)(d+i) = o;
  }
}

// prep (trimmed): cvt iwV/iwI/rsw + transpose-cvt ow.  Runs on blocks 512.. of p1big.
__device__ __forceinline__ void dev_prep2(const MegaArgs& P, int pblk, int tid, char* smem)
{
  const int g = pblk*256 + tid;
  cvt_range(P.iwV,  P.iwVb, 1048576, g);
  cvt_range(P.iwI,  P.iwIb, 1048576, g);
  cvt_range(P.rs_w, P.rswb, 131072,  g);
  float (*tile)[33] = (float(*)[33])smem;
  for (int t = pblk; t < 1024; t += 512){      // exactly 2 iters, uniform
    const int zz = t>>9, rem = t&511;
    const int r0 = (rem>>5)*32, c0 = (rem&31)*32;
    const float* src = zz? P.owI : P.owV;      // [512][1024]
    u16* dst = zz? P.owTI : P.owTV;            // [1024][512]
    __syncthreads();
    {
      const int r = tid>>3, c = (tid&7)*4;
      const float4 v = *(const float4*)(src + (size_t)(r0+r)*1024 + c0 + c);
      tile[r][c]=v.x; tile[r][c+1]=v.y; tile[r][c+2]=v.z; tile[r][c+3]=v.w;
    }
    __syncthreads();
    {
      const int cl = tid>>3, rl = (tid&7)*4;
      ushort4 o;
      o.x = f2bf(tile[rl+0][cl]); o.y = f2bf(tile[rl+1][cl]);
      o.z = f2bf(tile[rl+2][cl]); o.w = f2bf(tile[rl+3][cl]);
      *(ushort4*)(dst + (size_t)(c0+cl)*512 + r0 + rl) = o;
    }
  }
}

// k1 direct-from-f32: xr[m][n] = relu(bn( X^T . crw^T )), reg-staged bf16 tiles.
__device__ __forceinline__ void dev_k1f(const MegaArgs& P, int blk, int tid, char* smem)
{
  const int lane = tid&63, w = tid>>6;
  const int m0 = (blk>>3)*64, n0 = (blk&7)*64;
  const int img = m0>>10, hw0 = m0&1023;
  const float* __restrict__ Xp = (img<2? P.xV : P.xI) + (size_t)(img&1)*CIN*LQ;
  u16* As = (u16*)smem;                 // [64][64]
  u16* Bs = (u16*)(smem + 8192);
  const int m_off = (w>>1)*32, n_off = (w&1)*32;
  f32x4 acc[2][2];
  const f32x4 z = {0.f,0.f,0.f,0.f};
  #pragma unroll
  for (int mi=0;mi<2;++mi) for (int ni=0;ni<2;++ni) acc[mi][ni]=z;
  const int ar = tid&63, cb2 = (tid>>6)*16, aq0 = (tid>>6)*2;
  const int br = tid>>2, kb = (tid&3)*16, bq0 = (tid&3)*2;
  for (int t=0;t<4;++t){
    const int k0 = t*64;
    float va[16], vb[16];
    #pragma unroll
    for (int j=0;j<16;++j)
      va[j] = Xp[(size_t)(k0+cb2+j)*LQ + hw0 + ar];          // coalesced over ar
    #pragma unroll
    for (int j=0;j<16;j+=4)
      *(float4*)&vb[j] = *(const float4*)(P.cr_w + (size_t)(n0+br)*CIN + k0 + kb + j);
    if (t) __syncthreads();             // prev MFMA reads done before overwrite
    st8(As + ar*64 + (((aq0+0)^(ar&7))<<3), va);
    st8(As + ar*64 + (((aq0+1)^(ar&7))<<3), va+8);
    st8(Bs + br*64 + (((bq0+0)^(br&7))<<3), vb);
    st8(Bs + br*64 + (((bq0+1)^(br&7))<<3), vb+8);
    __syncthreads();
    #pragma unroll
    for (int ks=0;ks<2;++ks){
      const int c = ks*4 + (lane>>4);
      bf16x8 af[2], bb[2];
      #pragma unroll
      for (int mi=0;mi<2;++mi){
        const int R = m_off + mi*16 + (lane&15);
        af[mi] = *(const bf16x8*)(As + R*64 + ((c ^ (R&7))<<3));
      }
      #pragma unroll
      for (int ni=0;ni<2;++ni){
        const int R = n_off + ni*16 + (lane&15);
        bb[ni] = *(const bf16x8*)(Bs + R*64 + ((c ^ (R&7))<<3));
      }
      #pragma unroll
      for (int mi=0;mi<2;++mi)
        #pragma unroll
        for (int ni=0;ni<2;++ni)
          acc[mi][ni] = __builtin_amdgcn_mfma_f32_16x16x32_bf16(af[mi], bb[ni], acc[mi][ni], 0,0,0);
    }
  }
  #pragma unroll
  for (int mi=0;mi<2;++mi)
    #pragma unroll
    for (int ni=0;ni<2;++ni){
      const int n = n0 + n_off + ni*16 + (lane&15);
      const float s = P.cr_g[n]*rsqrtf(P.cr_v[n]+EPSF);
      const float t = P.cr_b[n] - P.cr_m[n]*s;
      #pragma unroll
      for (int rr=0;rr<4;++rr){
        const int m = m0 + m_off + mi*16 + ((lane>>4)<<2) + rr;
        P.xr[(size_t)m*DM + n] = fmaxf(fmaf(acc[mi][ni][rr], s, t), 0.f);
      }
    }
}

// W2 pre-GEMM (32 blocks): W2[p][q][kk] = sum_n rsw[q][n]*ow_p[n][kk]
__device__ __forceinline__ void dev_w2(const MegaArgs& P, int blk, int tid, char* smem)
{
  const int lane = tid&63, w = tid>>6;
  const int p = blk>>4, rem = blk&15;
  const int m0b = (rem>>3)*128, n0b = (rem&7)*128;
  f32x4 acc2[4][4];
  const f32x4 z = {0.f,0.f,0.f,0.f};
  #pragma unroll
  for (int mi=0;mi<4;++mi) for (int ni=0;ni<4;++ni) acc2[mi][ni]=z;
  gemm_dbuf<128,128>(P.rswb + (size_t)m0b*DM, (p? P.owTI : P.owTV) + (size_t)n0b*DM,
                     DM, (u16*)smem, acc2, tid);
  u16* __restrict__ orow = P.W2b + (size_t)p*256*1024;
  #pragma unroll
  for (int mi=0;mi<4;++mi)
    #pragma unroll
    for (int rr=0;rr<4;++rr){
      const int m = m0b + (w>>1)*64 + mi*16 + ((lane>>4)<<2) + rr;
      #pragma unroll
      for (int ni=0;ni<4;++ni){
        const int n = n0b + (w&1)*64 + ni*16 + (lane&15);
        orow[(size_t)m*1024 + n] = f2bf(acc2[mi][ni][rr]);
      }
    }
}

// P2: fused LN -> bf16 xn + pool partials (64 blocks)
__device__ __forceinline__ void dev_k2f(const MegaArgs& P, int blk, int tid, char* smem)
{
  const int sl = blk&15, img = blk>>4, p = img>>1;
  const int l = tid&63, w = tid>>6;
  float* pw = (float*)smem;                    // [4][512]
  const float* lg = (p? P.lnIg : P.lnVg) + l*8;
  const float* lb = (p? P.lnIb : P.lnVb) + l*8;
  float g8[8], b8[8];
  *(float4*)&g8[0] = *(const float4*)lg;  *(float4*)&g8[4] = *(const float4*)(lg+4);
  *(float4*)&b8[0] = *(const float4*)lb;  *(float4*)&b8[4] = *(const float4*)(lb+4);
  float acc[8] = {};
  const int rbase = img*1024 + sl*64 + w*16;
  for (int r=0; r<16; ++r){
    const int row = rbase + r;
    const float* base = P.xr + (size_t)row*DM + l*8;
    float v[8];
    *(float4*)&v[0] = *(const float4*)(base);
    *(float4*)&v[4] = *(const float4*)(base+4);
    float s=0.f, q=0.f;
    #pragma unroll
    for (int j=0;j<8;++j){ s += v[j]; q += v[j]*v[j]; acc[j] += v[j]; }
    #pragma unroll
    for (int off=32; off; off>>=1){ s += __shfl_down(s,off); q += __shfl_down(q,off); }
    s = __shfl(s,0); q = __shfl(q,0);
    const float mean = s*(1.f/DM);
    const float rstd = rsqrtf(fmaxf(q*(1.f/DM) - mean*mean, 0.f)+EPSF);
    float y[8];
    #pragma unroll
    for (int j=0;j<8;++j) y[j] = (v[j]-mean)*rstd*g8[j] + b8[j];
    st8(P.xn + (size_t)row*DM + l*8, y);
  }
  #pragma unroll
  for (int j=0;j<8;++j) pw[w*512 + l*8+j] = acc[j];
  __syncthreads();
  for (int ch=tid; ch<DM; ch+=256)
    P.part[((size_t)img*16 + sl)*DM + ch] = pw[ch]+pw[512+ch]+pw[1024+ch]+pw[1536+ch];
}

__device__ __forceinline__ void dev_lambda(const MegaArgs& P, int img, int tid, char* smem)
{
  const int p = img>>1;
  const float* w1 = p? P.w1I : P.w1V;  const float* b1 = p? P.b1I : P.b1V;
  const float* w2 = p? P.w2I : P.w2V;  const float* b2 = p? P.b2I : P.b2V;
  float* pool = (float*)smem;          // [512]
  float* hb   = pool + DM;             // [128]
  for (int ch=tid; ch<DM; ch+=256){
    float s=0.f;
    #pragma unroll
    for (int sl=0; sl<16; ++sl) s += P.part[((size_t)img*16 + sl)*DM + ch];
    pool[ch] = s * (1.f/LQ);
  }
  __syncthreads();
  if (tid<128){
    float h = b1[tid];
    const float* wr = w1 + (size_t)tid*DM;
    for (int o=0;o<DM;o+=4){
      const float4 wv = *(const float4*)(wr+o);
      h += pool[o]*wv.x + pool[o+1]*wv.y + pool[o+2]*wv.z + pool[o+3]*wv.w;
    }
    hb[tid] = fmaxf(h,0.f);
  }
  __syncthreads();
  if (tid==0){
    float v = b2[0];
    for (int j=0;j<128;++j) v += hb[j]*w2[j];
    P.lam[img] = sigm(v);
  }
}

// P3: k3 in-proj GEMM (512 blocks). Gate half (n0>=DI) stores 0.5*silu pre-applied.
__device__ __forceinline__ void dev_k3(const MegaArgs& P, int blk, int tid, char* smem)
{
  const int lane = tid&63, w = tid>>6;
  const int p = blk>>8, rem = blk&255;
  const int m0 = (rem>>4)*128, n0 = (rem&15)*128;
  const bool isGate = (n0 >= DI);
  const u16* A  = P.xn + (size_t)p*2048*DM;
  const u16* Bw = p? P.iwIb : P.iwVb;
  f32x4 acc[4][4];
  const f32x4 z = {0.f,0.f,0.f,0.f};
  #pragma unroll
  for (int mi=0;mi<4;++mi) for (int ni=0;ni<4;++ni) acc[mi][ni]=z;
  gemm_dbuf<128,128>(A + (size_t)m0*DM, Bw + (size_t)n0*DM, DM, (u16*)smem, acc, tid);
  u16* __restrict__ orow = P.xp + (size_t)p*2048*2048;
  #pragma unroll
  for (int mi=0;mi<4;++mi)
    #pragma unroll
    for (int rr=0;rr<4;++rr){
      const int m = m0 + (w>>1)*64 + mi*16 + ((lane>>4)<<2) + rr;
      #pragma unroll
      for (int ni=0;ni<4;++ni){
        const int n = n0 + (w&1)*64 + ni*16 + (lane&15);
        float v = acc[mi][ni][rr];
        if (isGate) v = 0.5f*v*sigm(v);
        orow[(size_t)m*2048 + n] = f2bf(v);
      }
    }
}

// P4: scan sweep 1 (raw chunk finals)
__device__ __forceinline__ void dev_k4s1(const MegaArgs& P, int blk, int tid, char* smem)
{
  const int p = blk>>8, rem = blk&255;
  const int c = rem>>3, rb = rem&7;
  const int row = rb*256 + tid;
  const int bb = rb>>2, il = (rb&3)*256, i = il + tid;
  u16* xs = (u16*)smem;                   // 16 KB
  {
    const u16* src = P.xp + ((size_t)(p*2048 + bb*1024 + c*TL))*2048 + il;
    const int r0 = tid>>5, cb = (tid&31)*8;
    #pragma unroll
    for (int rr=0; rr<TL; rr+=8)
      *(uint4*)(xs + (rr+r0)*256 + cb) = *(const uint4*)(src + (size_t)(rr+r0)*2048 + cb);
  }
  const float* Al = p? P.AI : P.AV;
  float a[16], uf[16], ub[16];
  #pragma unroll
  for (int s=0;s<16;s+=4){
    const float4 al = *(const float4*)(Al + (size_t)i*NS + s);
    a[s]=-expf(al.x); a[s+1]=-expf(al.y); a[s+2]=-expf(al.z); a[s+3]=-expf(al.w);
    uf[s]=0.f; uf[s+1]=0.f; uf[s+2]=0.f; uf[s+3]=0.f;
    ub[s]=0.f; ub[s+1]=0.f; ub[s+2]=0.f; ub[s+3]=0.f;
  }
  __syncthreads();
  #pragma unroll 4
  for (int tt=0; tt<TL; ++tt){
    const float xf = bf2f(xs[tt*256 + tid]);
    const float xb = bf2f(xs[(TL-1-tt)*256 + tid]);
    #pragma unroll
    for (int s=0;s<16;++s){
      uf[s] = fmaf(uf[s], a[s], xf);
      ub[s] = fmaf(ub[s], a[s], xb);
    }
  }
  u16* hpf = P.hfin + (((size_t)(p*2+0)*CH + c)*2048 + row)*NS;
  u16* hpb = P.hfin + (((size_t)(p*2+1)*CH + c)*2048 + row)*NS;
  st8(hpf, uf); st8(hpf+8, uf+8);
  st8(hpb, ub); st8(hpb+8, ub+8);
}

// P5: scan sweep 2 — in-register chunk prefix + register row-totals
__device__ __forceinline__ void dev_k4s2(const MegaArgs& P, int blk, int tid, char* smem)
{
  const int p = blk>>8, rem = blk&255;
  const int c = rem>>3, rb = rem&7;
  const int row = rb*256 + tid;
  const int bb = rb>>2, il = (rb&3)*256, i = il + tid;
  u16* xs = (u16*)smem;                   // 16 KB
  {
    const u16* src = P.xp + ((size_t)(p*2048 + bb*1024 + c*TL))*2048 + il;
    const int r0 = tid>>5, cb = (tid&31)*8;
    #pragma unroll
    for (int rr=0; rr<TL; rr+=8)
      *(uint4*)(xs + (rr+r0)*256 + cb) = *(const uint4*)(src + (size_t)(rr+r0)*2048 + cb);
  }
  const float* Al = p? P.AI : P.AV;
  const float* B0 = p? P.BI : P.BV;
  const float* B1 = p? P.BV : P.BI;
  const float* Cm = p? P.CI : P.CV;
  const float lm = P.lam[p*2+bb];
  float a[16], aT[16], dmix[16], uf[16], ub[16];
  #pragma unroll
  for (int s=0;s<16;s+=4){
    const float4 al = *(const float4*)(Al + (size_t)i*NS + s);
    const float4 b0 = *(const float4*)(B0 + (size_t)i*NS + s);
    const float4 b1 = *(const float4*)(B1 + (size_t)i*NS + s);
    const float4 cv = *(const float4*)(Cm + (size_t)i*NS + s);
    a[s]=-expf(al.x); a[s+1]=-expf(al.y); a[s+2]=-expf(al.z); a[s+3]=-expf(al.w);
    aT[s]  =expf((float)TL*al.x); aT[s+1]=expf((float)TL*al.y);
    aT[s+2]=expf((float)TL*al.z); aT[s+3]=expf((float)TL*al.w);
    dmix[s]  =(lm*b0.x+(1.f-lm)*b1.x)*cv.x;
    dmix[s+1]=(lm*b0.y+(1.f-lm)*b1.y)*cv.y;
    dmix[s+2]=(lm*b0.z+(1.f-lm)*b1.z)*cv.z;
    dmix[s+3]=(lm*b0.w+(1.f-lm)*b1.w)*cv.w;
    uf[s]=0.f; uf[s+1]=0.f; uf[s+2]=0.f; uf[s+3]=0.f;
    ub[s]=0.f; ub[s+1]=0.f; ub[s+2]=0.f; ub[s+3]=0.f;
  }
  const size_t cstride = (size_t)2048*NS;
  {
    const u16* hb = P.hfin + ((size_t)(p*2+0)*CH*2048 + row)*NS;
    if (c > 0){
      float fin[16];
      ld8(hb, fin); ld8(hb+8, fin+8);
      for (int j=1; j<c; ++j){
        float nx[16];
        ld8(hb + (size_t)j*cstride, nx); ld8(hb + (size_t)j*cstride + 8, nx+8);
        #pragma unroll
        for (int s=0;s<16;++s) uf[s] = fmaf(aT[s], uf[s], fin[s]);
        #pragma unroll
        for (int s=0;s<16;++s) fin[s] = nx[s];
      }
      #pragma unroll
      for (int s=0;s<16;++s) uf[s] = fmaf(aT[s], uf[s], fin[s]);
    }
  }
  {
    const u16* hb = P.hfin + ((size_t)(p*2+1)*CH*2048 + row)*NS;
    if (c < CH-1){
      float fin[16];
      ld8(hb + (size_t)(CH-1)*cstride, fin); ld8(hb + (size_t)(CH-1)*cstride + 8, fin+8);
      for (int j=CH-2; j>c; --j){
        float nx[16];
        ld8(hb + (size_t)j*cstride, nx); ld8(hb + (size_t)j*cstride + 8, nx+8);
        #pragma unroll
        for (int s=0;s<16;++s) ub[s] = fmaf(aT[s], ub[s], fin[s]);
        #pragma unroll
        for (int s=0;s<16;++s) fin[s] = nx[s];
      }
      #pragma unroll
      for (int s=0;s<16;++s) ub[s] = fmaf(aT[s], ub[s], fin[s]);
    }
  }
  __syncthreads();
  float tot[TL];
  #pragma unroll
  for (int tt=0; tt<TL; ++tt) tot[tt] = 0.f;
  #pragma unroll
  for (int tt=0; tt<TL; ++tt){
    const float xf = bf2f(xs[tt*256 + tid]);
    const float xb = bf2f(xs[(TL-1-tt)*256 + tid]);
    float yf0=0.f, yf1=0.f, yb0=0.f, yb1=0.f;
    #pragma unroll
    for (int s=0;s<16;s+=2){
      uf[s]   = fmaf(uf[s],   a[s],   xf);
      uf[s+1] = fmaf(uf[s+1], a[s+1], xf);
      ub[s]   = fmaf(ub[s],   a[s],   xb);
      ub[s+1] = fmaf(ub[s+1], a[s+1], xb);
      yf0 = fmaf(uf[s],   dmix[s],   yf0);
      yf1 = fmaf(uf[s+1], dmix[s+1], yf1);
      yb0 = fmaf(ub[s],   dmix[s],   yb0);
      yb1 = fmaf(ub[s+1], dmix[s+1], yb1);
    }
    tot[tt]      += (yf0+yf1);
    tot[TL-1-tt] += (yb0+yb1);
  }
  // epilogue: gate half of xp already holds 0.5*silu(g)
  #pragma unroll
  for (int tt=0; tt<TL; ++tt){
    const size_t mrow = (size_t)(p*2048 + bb*1024 + c*TL + tt);
    const float sg = bf2f(P.xp[mrow*2048 + DI + i]);
    P.comb[mrow*(size_t)DI + i] = f2bf(sg*tot[tt]);
  }
}

// P6: fused out-proj GEMM + BN + residual (32x64 tiles, 512 blocks)
__device__ __forceinline__ void dev_k5(const MegaArgs& P, int blk, int tid, char* smem)
{
  const int lane = tid&63, w = tid>>6;
  const int p = blk>>8, rem = blk&255;
  const int m0 = (rem>>2)*32, n0 = (rem&3)*64;
  const u16* A = P.comb + (size_t)p*2048*DI;
  const u16* B = P.W2b + (size_t)p*256*1024;
  f32x4 acc[1][2];
  const f32x4 z = {0.f,0.f,0.f,0.f};
  acc[0][0]=z; acc[0][1]=z;
  gemm_dbuf<32,64>(A + (size_t)m0*DI, B + (size_t)n0*DI, DI, (u16*)smem, acc, tid);
  const int bb = m0>>10;
  const int img = p*2 + bb;
  const float* xres = (p? P.xI : P.xV) + (size_t)bb*CIN*LQ;
  float* obase = P.out + (size_t)img*CIN*LQ;
  #pragma unroll
  for (int ni=0;ni<2;++ni){
    const int q = n0 + (w&1)*32 + ni*16 + (lane&15);
    const float s = P.rs_g[q]*rsqrtf(P.rs_v[q]+EPSF);
    const float t = P.rs_b[q] - P.rs_m[q]*s;
    const int m = m0 + (w>>1)*16 + ((lane>>4)<<2);
    const int hw = m & 1023;
    const float4 xv = *(const float4*)(xres + (size_t)q*LQ + hw);
    float4 o;
    o.x = fmaf(acc[0][ni][0], s, t) + xv.x;
    o.y = fmaf(acc[0][ni][1], s, t) + xv.y;
    o.z = fmaf(acc[0][ni][2], s, t) + xv.z;
    o.w = fmaf(acc[0][ni][3], s, t) + xv.w;
    *(float4*)(obase + (size_t)q*LQ + hw) = o;
  }
}

// ==================== pipeline kernels (6 launches) ====================
__global__ __launch_bounds__(256) void kk_p1big(MegaArgs P){
  __shared__ __align__(16) char smem[16384];
  if (blockIdx.x < 512) dev_k1f(P, blockIdx.x, threadIdx.x, smem);
  else                  dev_prep2(P, blockIdx.x - 512, threadIdx.x, smem);
}
__global__ __launch_bounds__(256) void kk_p2(MegaArgs P){
  __shared__ __align__(16) char smem[65536];
  if (blockIdx.x < 64) dev_k2f(P, blockIdx.x, threadIdx.x, smem);
  else                 dev_w2(P, blockIdx.x - 64, threadIdx.x, smem);
}
__global__ __launch_bounds__(256) void kk_p3(MegaArgs P){
  __shared__ __align__(16) char smem[65536];
  dev_k3(P, swz512(blockIdx.x), threadIdx.x, smem);
}
__global__ __launch_bounds__(256) void kk_p4(MegaArgs P){
  __shared__ __align__(16) char smem[16384];
  if (blockIdx.x < NBLK) dev_k4s1(P, swz512(blockIdx.x), threadIdx.x, smem);
  else                   dev_lambda(P, blockIdx.x - NBLK, threadIdx.x, smem);
}
__global__ __launch_bounds__(256,2) void kk_p5(MegaArgs P){
  __shared__ __align__(16) char smem[16384];
  dev_k4s2(P, swz512(blockIdx.x), threadIdx.x, smem);
}
__global__ __launch_bounds__(256) void kk_p6(MegaArgs P){
  __shared__ __align__(16) char smem[24576];      // (32+64)*256
  dev_k5(P, swz512(blockIdx.x), threadIdx.x, smem);
}

extern "C" void kernel_launch(void* const* d_in, const int* in_sizes, int n_in,
                              void* d_out, int out_size, void* d_ws, size_t ws_size,
                              hipStream_t stream)
{
  char* ws = (char*)d_ws;
  MegaArgs P;
  P.cr_w = (const float*)d_in[0];  P.cr_g = (const float*)d_in[1];
  P.cr_b = (const float*)d_in[2];  P.cr_m = (const float*)d_in[3];
  P.cr_v = (const float*)d_in[4];
  P.rs_w = (const float*)d_in[5];  P.rs_g = (const float*)d_in[6];
  P.rs_b = (const float*)d_in[7];  P.rs_m = (const float*)d_in[8];
  P.rs_v = (const float*)d_in[9];
  P.lnVg = (const float*)d_in[10]; P.lnVb = (const float*)d_in[11];
  P.iwV  = (const float*)d_in[12]; P.AV   = (const float*)d_in[13];
  P.BV   = (const float*)d_in[14]; P.CV   = (const float*)d_in[15];
  P.owV  = (const float*)d_in[16];
  P.w1V  = (const float*)d_in[17]; P.b1V  = (const float*)d_in[18];
  P.w2V  = (const float*)d_in[19]; P.b2V  = (const float*)d_in[20];
  P.lnIg = (const float*)d_in[21]; P.lnIb = (const float*)d_in[22];
  P.iwI  = (const float*)d_in[23]; P.AI   = (const float*)d_in[24];
  P.BI   = (const float*)d_in[25]; P.CI   = (const float*)d_in[26];
  P.owI  = (const float*)d_in[27];
  P.w1I  = (const float*)d_in[28]; P.b1I  = (const float*)d_in[29];
  P.w2I  = (const float*)d_in[30]; P.b2I  = (const float*)d_in[31];
  P.xV   = (const float*)d_in[32]; P.xI   = (const float*)d_in[33];
  P.out  = (float*)d_out;
  // ws layout (~47.8 MB peak):
  P.xr   = (float*)(ws + 0);            // [4096][512] f32          8,388,608
  P.xn   = (u16*)  (ws + 8388608);      // [2][2048][512] bf16      4,194,304
  P.lam  = (float*)(ws + 12582912);     // [4] f32 (+pad)                 512
  P.iwVb = (u16*)  (ws + 12583424);     // [2048][512] bf16         2,097,152
  P.iwIb = (u16*)  (ws + 14680576);     // [2048][512] bf16         2,097,152
  P.owTV = (u16*)  (ws + 16777728);     // [1024][512] bf16         1,048,576
  P.owTI = (u16*)  (ws + 17826304);     // [1024][512] bf16         1,048,576
  P.rswb = (u16*)  (ws + 18874880);     // [256][512] bf16            262,144
  P.W2b  = (u16*)  (ws + 21496320);     // [2][256][1024] bf16      1,048,576
  P.part = (float*)(ws + 22544896);     // [4][16][512] f32           131,072
  P.xp   = (u16*)  (ws + 22675968);     // [2][2048][2048] bf16    16,777,216
  P.comb = (u16*)  (ws + 39453184);     // [2][2048][1024] bf16     8,388,608
  P.hfin = (u16*)  (ws + 0);            // [4][32][2048][16] bf16   8,388,608 (aliases xr; xr dead after p2)

  kk_p1big<<<dim3(1024),  dim3(256), 0, stream>>>(P);
  kk_p2   <<<dim3(96),    dim3(256), 0, stream>>>(P);
  kk_p3   <<<dim3(NBLK),  dim3(256), 0, stream>>>(P);
  kk_p4   <<<dim3(NBLK+4),dim3(256), 0, stream>>>(P);
  kk_p5   <<<dim3(NBLK),  dim3(256), 0, stream>>>(P);
  kk_p6   <<<dim3(NBLK),  dim3(256), 0, stream>>>(P);
}